// Round 5
// baseline (286.721 us; speedup 1.0000x reference)
//
#include <hip/hip_runtime.h>
#include <cstdint>
#include <cstddef>

#define BB 16
#define NN 4096
#define CC 80
#define MAXD 100
#define IOU_T 0.5f
#define CONF_T 0.5f
#define RSTRIDE 81
#define PER_B (MAXD * 4 + MAXD * CC)   // 8400 output elems per batch
#define NWORDS (NN / 64)
#define BCAP 2048
#define SEGSZ 2048
#define HH 2048                        // head size for mask matrix
#define HW 32                          // head words (HH/64)

// ---- workspace layout (fast path) ----
#define WS_KEYS   0x000000             // [B*N] u64 (og int list overlays)
#define WS_Y1S    0x080000             // [B*N] f32 each
#define WS_X1S    0x0C0000
#define WS_Y2S    0x100000
#define WS_X2S    0x140000
#define WS_ARS    0x180000
#define WS_NLIST  0x1C0000             // [B] int
#define WS_KIDX   0x1C0100             // [B*100] int
#define WS_CNT    0x1C2000             // [B] int
#define WS_MASK   0x200000             // [B*HH*HW] u64 = 8 MB
#define WS_NEED   0xA00000             // 10.5 MB

// ---------------------------------------------------------------------------
// K1: softmax of (10x)^2 per row, one THREAD per row, 128 rows/block.
// numpy pairwise-8 sum DAG for s (bitwise == np); score = IEEE fl(1/s).
// ---------------------------------------------------------------------------
__global__ __launch_bounds__(128) void k_softmax(const float* __restrict__ cls_in,
                                                 float* __restrict__ probs,
                                                 uint64_t* __restrict__ keys) {
#pragma clang fp contract(off)
    __shared__ float buf[128 * RSTRIDE];
    int t = threadIdx.x;
    size_t gbase = (size_t)blockIdx.x * 128 * CC;

    for (int i = t; i < 128 * CC; i += 128) {
        int r = i / CC, c = i - r * CC;
        buf[r * RSTRIDE + c] = cls_in[gbase + i];
    }
    __syncthreads();

    float* row = buf + t * RSTRIDE;

    float m = -3.402823466e+38f;
    for (int c = 0; c < CC; ++c) {
        float y = row[c] * 10.0f;
        float z = y * y;
        m = fmaxf(m, z);
    }
    for (int c = 0; c < CC; ++c) {
        float y = row[c] * 10.0f;
        float z = y * y;
        row[c] = expf(z - m);
    }
    float r8[8];
    #pragma unroll
    for (int j = 0; j < 8; ++j) r8[j] = row[j];
    for (int i = 8; i < CC; i += 8) {
        #pragma unroll
        for (int j = 0; j < 8; ++j) r8[j] += row[i + j];
    }
    float s = ((r8[0] + r8[1]) + (r8[2] + r8[3])) + ((r8[4] + r8[5]) + (r8[6] + r8[7]));

    float score = 1.0f / s;
    for (int c = 0; c < CC; ++c) row[c] = row[c] * score;

    int gw = blockIdx.x * 128 + t;
    unsigned n = (unsigned)(gw & (NN - 1));
    keys[gw] = ((uint64_t)__float_as_uint(score) << 32)
             | (uint64_t)(0xFFFFFFFFu - n);

    __syncthreads();
    for (int i = t; i < 128 * CC; i += 128) {
        int r = i / CC, c = i - r * CC;
        probs[gbase + i] = buf[r * RSTRIDE + c];
    }
}

// ---------------------------------------------------------------------------
// K2: partition + B-sort + sorted corner arrays. ONE WAVE per batch
// (barriers are wave-cheap; ballot-scan compaction).
//  A = {score==1.0f} in idx order; B = (0.5,1.0) bitonic-sorted (dyn size);
//  C discarded. og[] (over keys) = sorted original-index list.
// ---------------------------------------------------------------------------
__global__ __launch_bounds__(64) void k_prep(uint64_t* keys,
                                             const float* __restrict__ boxes,
                                             float* __restrict__ y1s, float* __restrict__ x1s,
                                             float* __restrict__ y2s, float* __restrict__ x2s,
                                             float* __restrict__ ars,
                                             int* __restrict__ nlist_g) {
#pragma clang fp contract(off)
    __shared__ uint64_t bbuf[BCAP];
    int b = blockIdx.x, lane = threadIdx.x;
    uint64_t* kb = keys + (size_t)b * NN;
    int* og = (int*)kb;
    uint64_t lmlt = (1ull << lane) - 1ull;

    int cntA = 0, cntB = 0;
    for (int k = 0; k < NN / 64; ++k) {
        uint64_t key = kb[64 * k + lane];
        unsigned hi = (unsigned)(key >> 32);
        bool isA = (hi == 0x3F800000u);
        bool isB = !isA && (__uint_as_float(hi) > CONF_T);
        uint64_t balA = __ballot(isA), balB = __ballot(isB);
        if (isA) og[cntA + __popcll(balA & lmlt)] = 64 * k + lane;
        if (isB) {
            int p = cntB + __popcll(balB & lmlt);
            if (p < BCAP) bbuf[p] = key;
        }
        cntA += __popcll(balA);
        cntB += __popcll(balB);
    }
    int cntBc = cntB < BCAP ? cntB : BCAP;
    int P2 = 64; while (P2 < cntBc) P2 <<= 1;
    for (int i = lane; i < P2; i += 64) if (i >= cntBc) bbuf[i] = 0;
    __syncthreads();
    for (unsigned k2 = 2; k2 <= (unsigned)P2; k2 <<= 1) {
        for (unsigned j = k2 >> 1; j > 0; j >>= 1) {
            for (unsigned i = lane; i < (unsigned)P2; i += 64) {
                unsigned p = i ^ j;
                if (p > i) {
                    uint64_t va = bbuf[i], vb = bbuf[p];
                    bool desc = ((i & k2) == 0);
                    if (desc ? (va < vb) : (va > vb)) { bbuf[i] = vb; bbuf[p] = va; }
                }
            }
            __syncthreads();
        }
    }
    for (int i = lane; i < cntBc; i += 64)
        og[cntA + i] = (int)(0xFFFFFFFFu - (unsigned)(bbuf[i] & 0xFFFFFFFFull));
    int nl = cntA + cntBc;
    if (lane == 0) nlist_g[b] = nl;
    __syncthreads();

    // sorted corner/area arrays
    const float* bxp = boxes + (size_t)b * NN * 4;
    size_t bN = (size_t)b * NN;
    for (int i = lane; i < nl; i += 64) {
        int o = og[i];
        float b0 = bxp[o * 4 + 0], b1 = bxp[o * 4 + 1];
        float b2 = bxp[o * 4 + 2], b3 = bxp[o * 4 + 3];
        float y1 = fminf(b0, b2), y2 = fmaxf(b0, b2);
        float x1 = fminf(b1, b3), x2 = fmaxf(b1, b3);
        y1s[bN + i] = y1; x1s[bN + i] = x1;
        y2s[bN + i] = y2; x2s[bN + i] = x2;
        ars[bN + i] = (y2 - y1) * (x2 - x1);
    }
}

// ---------------------------------------------------------------------------
// K3: head suppression-mask matrix. Block = (col-tile tj, batch b):
// cols j = 64tj..64tj+63 (lane), rows i = 0..min(Hc,64tj+63) wave-strided.
// Word = ballot(iou(i,j)>thr && j>i). Rows staged in LDS (broadcast reads).
// ---------------------------------------------------------------------------
__global__ __launch_bounds__(1024) void k_iou(const float* __restrict__ y1s, const float* __restrict__ x1s,
                                              const float* __restrict__ y2s, const float* __restrict__ x2s,
                                              const float* __restrict__ ars,
                                              const int* __restrict__ nlist_g,
                                              uint64_t* __restrict__ mask) {
#pragma clang fp contract(off)
    __shared__ float ry1[HH], rx1[HH], ry2[HH], rx2[HH], rar[HH];
    int tj = blockIdx.x, b = blockIdx.y;
    int lane = threadIdx.x & 63, wv = threadIdx.x >> 6;
    int nl = nlist_g[b];
    int Hc = nl < HH ? nl : HH;
    int rmax = 64 * tj + 63; if (rmax > Hc) rmax = Hc;
    size_t bN = (size_t)b * NN;

    int j = 64 * tj + lane;
    bool jv = j < Hc;
    float cy1 = 0.f, cx1 = 0.f, cy2 = 0.f, cx2 = 0.f, car = 0.f;
    if (jv) { cy1 = y1s[bN + j]; cx1 = x1s[bN + j]; cy2 = y2s[bN + j]; cx2 = x2s[bN + j]; car = ars[bN + j]; }

    for (int i = threadIdx.x; i < rmax; i += 1024) {
        ry1[i] = y1s[bN + i]; rx1[i] = x1s[bN + i];
        ry2[i] = y2s[bN + i]; rx2[i] = x2s[bN + i];
        rar[i] = ars[bN + i];
    }
    __syncthreads();

    uint64_t* mrow = mask + (((size_t)b * HH) << 5) + tj;
    for (int i = wv; i < rmax; i += 16) {
        float a1 = ry1[i], c1 = rx1[i], a2 = ry2[i], c2 = rx2[i], aa = rar[i];
        float ih = fmaxf(0.f, fminf(cy2, a2) - fmaxf(cy1, a1));
        float iw = fmaxf(0.f, fminf(cx2, c2) - fmaxf(cx1, c1));
        float inter = ih * iw;
        float uni = (aa + car) - inter;
        bool s = jv && (j > i) && (inter > 0.f) && (inter / uni > IOU_T);
        uint64_t w = __ballot(s);
        if (lane == 0) mrow[(size_t)i << 5] = w;
    }
}

// ---------------------------------------------------------------------------
// K4: sweep. One block/batch; phase A = wave0 barrier-free register-bitmap
// sweep over head (mask-row loads); phase B = all waves suppress tail vs
// head-keeps; phase C = wave0 walks surviving tail vs tail-keeps.
// ---------------------------------------------------------------------------
__global__ __launch_bounds__(1024) void k_sweep(const uint64_t* __restrict__ mask,
                                                const float* __restrict__ y1s, const float* __restrict__ x1s,
                                                const float* __restrict__ y2s, const float* __restrict__ x2s,
                                                const float* __restrict__ ars,
                                                const int* __restrict__ nlist_g,
                                                const uint64_t* __restrict__ keys,  // og overlay
                                                int* __restrict__ kidx_out,
                                                int* __restrict__ cnt_out) {
#pragma clang fp contract(off)
    __shared__ float kky1[MAXD], kkx1[MAXD], kky2[MAXD], kkx2[MAXD], kkar[MAXD];
    __shared__ int   kkidx[MAXD];
    __shared__ uint64_t tailw[HW];
    __shared__ int kA_s, ktot_s;

    int b = blockIdx.x;
    int tid = threadIdx.x, lane = tid & 63, wv = tid >> 6;
    int nl = nlist_g[b];
    int Hc = nl < HH ? nl : HH;
    size_t bN = (size_t)b * NN;
    const int* og = (const int*)(keys + bN);
    const uint64_t* mb = mask + (((size_t)b * HH) << 5);

    if (tid == 0) { kA_s = 0; ktot_s = 0; }
    for (int i = tid; i < HW; i += 1024) tailw[i] = 0;
    __syncthreads();

    // ---- phase A: wave0 head sweep ----
    if (wv == 0) {
        int lo = 64 * lane;
        uint64_t live;
        if (Hc <= lo) live = 0;
        else if (Hc >= lo + 64) live = ~0ull;
        else live = (1ull << (Hc - lo)) - 1ull;

        int kept = 0;
        while (kept < MAXD) {
            uint64_t bal = __ballot(live != 0);
            if (!bal) break;
            int fl = __ffsll((unsigned long long)bal) - 1;
            uint64_t w0 = __shfl(live, fl);
            int c = 64 * fl + (__ffsll((unsigned long long)w0) - 1);

            // loads (overlap): mask row + candidate data
            uint64_t rw = (lane < HW) ? mb[(((size_t)c) << 5) + lane] : 0;
            float ay1 = y1s[bN + c], ax1 = x1s[bN + c];
            float ay2 = y2s[bN + c], ax2 = x2s[bN + c];
            float aar = ars[bN + c];
            int oidx = og[c];

            int ct = c >> 6, cb = c & 63;
            if (lane < ct) rw = 0;
            else if (lane == ct) rw &= (cb == 63) ? 0ull : (~0ull << (cb + 1));
            live &= ~rw;
            if (lane == ct) live &= ~(1ull << cb);

            if (lane == 0) {
                kky1[kept] = ay1; kkx1[kept] = ax1;
                kky2[kept] = ay2; kkx2[kept] = ax2;
                kkar[kept] = aar; kkidx[kept] = oidx;
            }
            ++kept;
        }
        if (lane == 0) { kA_s = kept; ktot_s = kept; }
    }
    __syncthreads();

    // ---- phase B: parallel tail suppression vs head keeps ----
    int kA = kA_s;
    if (nl > HH && kA < MAXD) {
        for (int rep = 0; rep < 2; ++rep) {
            int c = HH + rep * 1024 + tid;
            bool sup = (c >= nl);
            float y1 = y1s[bN + c], x1 = x1s[bN + c];
            float y2 = y2s[bN + c], x2 = x2s[bN + c];
            float ar = ars[bN + c];
            for (int q = 0; q < kA; ++q) {
                float ih = fmaxf(0.f, fminf(y2, kky2[q]) - fmaxf(y1, kky1[q]));
                float iw = fmaxf(0.f, fminf(x2, kkx2[q]) - fmaxf(x1, kkx1[q]));
                float inter = ih * iw;
                float uni = (ar + kkar[q]) - inter;
                sup = sup || (inter > 0.f && inter / uni > IOU_T);
            }
            uint64_t balS = __ballot(!sup);
            if (lane == 0) tailw[rep * 16 + wv] = balS;
        }
    }
    __syncthreads();

    // ---- phase C: wave0 walks surviving tail candidates ----
    if (wv == 0 && nl > HH && kA < MAXD) {
        uint64_t tlive = (lane >= 32) ? tailw[lane - 32] : 0;
        int kept = kA;
        while (kept < MAXD) {
            uint64_t bal = __ballot(tlive != 0);
            if (!bal) break;
            int fl = __ffsll((unsigned long long)bal) - 1;
            uint64_t w0 = __shfl(tlive, fl);
            int bit = __ffsll((unsigned long long)w0) - 1;
            int c = HH + 64 * (fl - 32) + bit;
            if (lane == fl) tlive &= tlive - 1;   // clear lowest (found) bit

            float y1 = y1s[bN + c], x1 = x1s[bN + c];
            float y2 = y2s[bN + c], x2 = x2s[bN + c];
            float ar = ars[bN + c];
            bool hit = false;
            for (int q0 = kA; q0 < kept; q0 += 64) {
                int qi = q0 + lane;
                bool p = false;
                if (qi < kept) {
                    float ih = fmaxf(0.f, fminf(y2, kky2[qi]) - fmaxf(y1, kky1[qi]));
                    float iw = fmaxf(0.f, fminf(x2, kkx2[qi]) - fmaxf(x1, kkx1[qi]));
                    float inter = ih * iw;
                    float uni = (ar + kkar[qi]) - inter;
                    p = (inter > 0.f) && (inter / uni > IOU_T);
                }
                if (__ballot(p)) { hit = true; break; }
            }
            if (!hit) {
                if (lane == 0) {
                    kky1[kept] = y1; kkx1[kept] = x1;
                    kky2[kept] = y2; kkx2[kept] = x2;
                    kkar[kept] = ar; kkidx[kept] = og[c];
                }
                ++kept;
            }
        }
        if (lane == 0) ktot_s = kept;
    }
    __syncthreads();

    int kt = ktot_s;
    if (tid == 0) cnt_out[b] = kt;
    for (int i = tid; i < MAXD; i += 1024)
        kidx_out[b * MAXD + i] = (i < kt) ? kkidx[i] : 0;
}

// ---------------------------------------------------------------------------
// K5: wide parallel gather (unchanged).
// ---------------------------------------------------------------------------
__global__ __launch_bounds__(256) void k_gather(const float* __restrict__ boxes,
                                                const float* __restrict__ probs,
                                                const int* __restrict__ kidx,
                                                const int* __restrict__ cnt,
                                                float* __restrict__ out_box,
                                                float* __restrict__ out_cls) {
    int u = blockIdx.x * 256 + threadIdx.x;
    if (u >= BB * PER_B) return;
    int b = u / PER_B;
    int r = u - b * PER_B;
    int count = cnt[b];
    float val = 0.0f;
    if (r < MAXD * 4) {
        int t = r >> 2, e = r & 3;
        if (t < count) {
            int idx = kidx[b * MAXD + t];
            val = boxes[((size_t)b * NN + idx) * 4 + e];
        }
        out_box[(size_t)b * MAXD * 4 + r] = val;
    } else {
        int q = r - MAXD * 4;
        int t = q / CC, c = q - t * CC;
        if (t < count) {
            int idx = kidx[b * MAXD + t];
            val = probs[((size_t)b * NN + idx) * CC + c];
        }
        out_cls[(size_t)b * MAXD * CC + q] = val;
    }
}

// ---------------------------------------------------------------------------
// FALLBACK (ws too small): round-4 fused k_nms — verified passing.
// ---------------------------------------------------------------------------
__global__ __launch_bounds__(1024) void k_nms_fb(uint64_t* keys,
                                                 const float* __restrict__ boxes,
                                                 int* __restrict__ kidx_out,
                                                 int* __restrict__ cnt_out) {
#pragma clang fp contract(off)
    __shared__ float sy1[SEGSZ], sx1[SEGSZ], sy2[SEGSZ], sx2[SEGSZ];
    __shared__ int   soidx[SEGSZ];
    __shared__ uint64_t bbuf[BCAP];
    __shared__ uint64_t sup[NWORDS];
    __shared__ float ky1[MAXD], kx1[MAXD], ky2[MAXD], kx2[MAXD], kar[MAXD];
    __shared__ int   keptidx[MAXD];
    __shared__ int   wsumA[16], wsumB[16];
    __shared__ int   keptcnt_s, ctrl_s, seg_s;

    const int tid = threadIdx.x, lane = tid & 63, wv = tid >> 6;
    const int b = blockIdx.x;
    const uint64_t* kb = keys + (size_t)b * NN;
    const float* bxp = boxes + (size_t)b * NN * 4;
    int* og = (int*)(keys + (size_t)b * NN);

    uint64_t myk[4]; bool fa[4], fb[4];
    int asum = 0, bsum = 0;
    for (int k = 0; k < 4; ++k) {
        uint64_t key = kb[4 * tid + k]; myk[k] = key;
        unsigned hi = (unsigned)(key >> 32);
        fa[k] = (hi == 0x3F800000u);
        fb[k] = (__uint_as_float(hi) > CONF_T) && !fa[k];
        asum += fa[k] ? 1 : 0; bsum += fb[k] ? 1 : 0;
    }
    int ia = asum, ib = bsum;
    for (int off = 1; off < 64; off <<= 1) {
        int va = __shfl_up(ia, off), vb = __shfl_up(ib, off);
        if (lane >= off) { ia += va; ib += vb; }
    }
    if (lane == 63) { wsumA[wv] = ia; wsumB[wv] = ib; }
    __syncthreads();
    int baseA = 0, baseB = 0, cntA = 0, cntB = 0;
    for (int w2 = 0; w2 < 16; ++w2) {
        if (w2 < wv) { baseA += wsumA[w2]; baseB += wsumB[w2]; }
        cntA += wsumA[w2]; cntB += wsumB[w2];
    }
    int pA = baseA + (ia - asum);
    int pB = baseB + (ib - bsum);
    for (int k = 0; k < 4; ++k) {
        if (fa[k]) og[pA++] = 4 * tid + k;
        if (fb[k]) { if (pB < BCAP) bbuf[pB] = myk[k]; pB++; }
    }
    int cntBc = cntB < BCAP ? cntB : BCAP;
    int nlist = cntA + cntBc;
    if (tid == 0) { keptcnt_s = 0; seg_s = 0; }
    for (int i = tid; i < BCAP; i += 1024) if (i >= cntB) bbuf[i] = 0;
    __syncthreads();

    for (unsigned k2 = 2; k2 <= BCAP; k2 <<= 1) {
        for (unsigned j = k2 >> 1; j > 0; j >>= 1) {
            for (unsigned i = tid; i < BCAP; i += 1024) {
                unsigned p = i ^ j;
                if (p > i) {
                    uint64_t va = bbuf[i], vb = bbuf[p];
                    bool desc = ((i & k2) == 0);
                    if (desc ? (va < vb) : (va > vb)) { bbuf[i] = vb; bbuf[p] = va; }
                }
            }
            __syncthreads();
        }
    }
    for (int i = tid; i < cntBc; i += 1024)
        og[cntA + i] = (int)(0xFFFFFFFFu - (unsigned)(bbuf[i] & 0xFFFFFFFFull));
    if (tid < NWORDS) {
        int lo = tid * 64;
        uint64_t mm;
        if (nlist <= lo) mm = ~0ull;
        else if (nlist >= lo + 64) mm = 0ull;
        else mm = (~0ull) << (nlist - lo);
        sup[tid] = mm;
    }
    __syncthreads();

    for (int i = tid; i < SEGSZ; i += 1024) {
        if (i < nlist) {
            int o = og[i];
            soidx[i] = o;
            const float* bp = bxp + (size_t)o * 4;
            float b0 = bp[0], b1 = bp[1], b2 = bp[2], b3 = bp[3];
            sy1[i] = fminf(b0, b2); sy2[i] = fmaxf(b0, b2);
            sx1[i] = fminf(b1, b3); sx2[i] = fmaxf(b1, b3);
        }
    }
    __syncthreads();

    int curw = 0, segr = 0;
    while (true) {
        if (tid == 0) {
            int code = -1;
            for (;;) {
                int wend = (segr + 1) * (SEGSZ / 64);
                if (curw >= wend) {
                    if (segr == 0 && nlist > SEGSZ) {
                        code = -2; segr = 1; seg_s = 1; curw = SEGSZ / 64;
                    } else code = -1;
                    break;
                }
                uint64_t live = ~sup[curw];
                if (live) {
                    int j = __ffsll((unsigned long long)live) - 1;
                    int sel = curw * 64 + j;
                    int li = sel - segr * SEGSZ;
                    int kc = keptcnt_s;
                    keptidx[kc] = soidx[li];
                    ky1[kc] = sy1[li]; kx1[kc] = sx1[li];
                    ky2[kc] = sy2[li]; kx2[kc] = sx2[li];
                    kar[kc] = (sy2[li] - sy1[li]) * (sx2[li] - sx1[li]);
                    keptcnt_s = kc + 1;
                    sup[curw] |= (1ull << j);
                    code = (kc + 1 >= MAXD) ? -1 : sel;
                    break;
                }
                ++curw;
            }
            ctrl_s = code;
        }
        __syncthreads();
        int c = ctrl_s;
        if (c == -1) break;

        if (c == -2) {
            for (int i = tid; i < SEGSZ; i += 1024) {
                int gi = SEGSZ + i;
                if (gi < nlist) {
                    int o = og[gi];
                    soidx[i] = o;
                    const float* bp = bxp + (size_t)o * 4;
                    float b0 = bp[0], b1 = bp[1], b2 = bp[2], b3 = bp[3];
                    sy1[i] = fminf(b0, b2); sy2[i] = fmaxf(b0, b2);
                    sx1[i] = fminf(b1, b3); sx2[i] = fmaxf(b1, b3);
                }
            }
            __syncthreads();
            int kc = keptcnt_s;
            for (int k = 0; k < 2; ++k) {
                int li = tid + k * 1024;
                float y1 = sy1[li], y2 = sy2[li], x1 = sx1[li], x2 = sx2[li];
                float ar = (y2 - y1) * (x2 - x1);
                bool s = false;
                for (int q = 0; q < kc; ++q) {
                    float ih = fmaxf(0.f, fminf(y2, ky2[q]) - fmaxf(y1, ky1[q]));
                    float iw = fmaxf(0.f, fminf(x2, kx2[q]) - fmaxf(x1, kx1[q]));
                    float inter = ih * iw;
                    float uni = (ar + kar[q]) - inter;
                    s = s || (inter > 0.f && inter / uni > IOU_T);
                }
                uint64_t bal = __ballot(s);
                if (lane == 0 && bal) {
                    int word = (SEGSZ + k * 1024 + wv * 64) >> 6;
                    sup[word] |= bal;
                }
            }
            __syncthreads();
            continue;
        }

        int sg = seg_s;
        int cl = c - sg * SEGSZ;
        float cy1 = sy1[cl], cy2 = sy2[cl], cx1 = sx1[cl], cx2 = sx2[cl];
        float car = (cy2 - cy1) * (cx2 - cx1);
        for (int k = 0; k < 2; ++k) {
            int li = tid + k * 1024;
            float y1 = sy1[li], y2 = sy2[li], x1 = sx1[li], x2 = sx2[li];
            float ar = (y2 - y1) * (x2 - x1);
            float ih = fmaxf(0.f, fminf(y2, cy2) - fmaxf(y1, cy1));
            float iw = fmaxf(0.f, fminf(x2, cx2) - fmaxf(x1, cx1));
            float inter = ih * iw;
            float uni = (ar + car) - inter;
            bool s = (inter > 0.f) && (inter / uni > IOU_T);
            uint64_t bal = __ballot(s);
            if (lane == 0 && bal) {
                int word = (sg * SEGSZ + k * 1024 + wv * 64) >> 6;
                sup[word] |= bal;
            }
        }
        __syncthreads();
    }

    if (tid == 0) cnt_out[b] = keptcnt_s;
    for (int i = tid; i < MAXD; i += 1024)
        kidx_out[b * MAXD + i] = (i < keptcnt_s) ? keptidx[i] : 0;
}

extern "C" void kernel_launch(void* const* d_in, const int* in_sizes, int n_in,
                              void* d_out, int out_size, void* d_ws, size_t ws_size,
                              hipStream_t stream) {
    const float* boxes = (const float*)d_in[0];   // [B,N,4]
    const float* cls   = (const float*)d_in[1];   // [B,N,C]
    float* out = (float*)d_out;
    float* out_box = out;                                                  // [B,100,4]
    float* out_cls = out + (size_t)BB * MAXD * 4;                          // [B,100,80]
    float* probs   = out + (size_t)BB * MAXD * 4 + (size_t)BB * MAXD * CC; // [B,N,80]

    char* ws = (char*)d_ws;
    uint64_t* keys = (uint64_t*)(ws + WS_KEYS);

    k_softmax<<<(BB * NN) / 128, 128, 0, stream>>>(cls, probs, keys);

    if (ws_size >= (size_t)WS_NEED) {
        float* y1s = (float*)(ws + WS_Y1S);
        float* x1s = (float*)(ws + WS_X1S);
        float* y2s = (float*)(ws + WS_Y2S);
        float* x2s = (float*)(ws + WS_X2S);
        float* ars = (float*)(ws + WS_ARS);
        int* nlist = (int*)(ws + WS_NLIST);
        int* kidx  = (int*)(ws + WS_KIDX);
        int* cnt   = (int*)(ws + WS_CNT);
        uint64_t* mask = (uint64_t*)(ws + WS_MASK);

        k_prep<<<BB, 64, 0, stream>>>(keys, boxes, y1s, x1s, y2s, x2s, ars, nlist);
        k_iou<<<dim3(HW, BB), 1024, 0, stream>>>(y1s, x1s, y2s, x2s, ars, nlist, mask);
        k_sweep<<<BB, 1024, 0, stream>>>(mask, y1s, x1s, y2s, x2s, ars, nlist,
                                         keys, kidx, cnt);
        k_gather<<<(BB * PER_B + 255) / 256, 256, 0, stream>>>(boxes, probs, kidx, cnt,
                                                               out_box, out_cls);
    } else {
        int* kidx = (int*)(ws + (size_t)BB * NN * sizeof(uint64_t));
        int* cnt  = kidx + BB * MAXD;
        k_nms_fb<<<BB, 1024, 0, stream>>>(keys, boxes, kidx, cnt);
        k_gather<<<(BB * PER_B + 255) / 256, 256, 0, stream>>>(boxes, probs, kidx, cnt,
                                                               out_box, out_cls);
    }
}

// Round 6
// 219.222 us; speedup vs baseline: 1.3079x; 1.3079x over previous
//
#include <hip/hip_runtime.h>
#include <cstdint>
#include <cstddef>

#define BB 16
#define NN 4096
#define CC 80
#define MAXD 100
#define IOU_T 0.5f
#define CONF_T 0.5f
#define RSTRIDE 81
#define PER_B (MAXD * 4 + MAXD * CC)   // 8400 output elems per batch
#define NWORDS (NN / 64)
#define BCAP 2048
#define SEGSZ 2048
#define HH 2048                        // head size for mask matrix
#define HW 32                          // head words (HH/64)

// ---- workspace layout (fast path) ----
#define WS_KEYS   0x000000             // [B*N] u64 (og int list overlays)
#define WS_Y1S    0x080000             // [B*N] f32 each
#define WS_X1S    0x0C0000
#define WS_Y2S    0x100000
#define WS_X2S    0x140000
#define WS_ARS    0x180000
#define WS_NLIST  0x1C0000             // [B] int
#define WS_KIDX   0x1C0100             // [B*100] int
#define WS_CNT    0x1C2000             // [B] int
#define WS_MASK   0x200000             // [B*HH*HW] u64 = 8 MB
#define WS_NEED   0xA00000             // 10.5 MB

// ---------------------------------------------------------------------------
// K1: softmax of (10x)^2 per row, one THREAD per row, 128 rows/block.
// numpy pairwise-8 sum DAG for s (bitwise == np); score = IEEE fl(1/s).
// ---------------------------------------------------------------------------
__global__ __launch_bounds__(128) void k_softmax(const float* __restrict__ cls_in,
                                                 float* __restrict__ probs,
                                                 uint64_t* __restrict__ keys) {
#pragma clang fp contract(off)
    __shared__ float buf[128 * RSTRIDE];
    int t = threadIdx.x;
    size_t gbase = (size_t)blockIdx.x * 128 * CC;

    for (int i = t; i < 128 * CC; i += 128) {
        int r = i / CC, c = i - r * CC;
        buf[r * RSTRIDE + c] = cls_in[gbase + i];
    }
    __syncthreads();

    float* row = buf + t * RSTRIDE;

    float m = -3.402823466e+38f;
    for (int c = 0; c < CC; ++c) {
        float y = row[c] * 10.0f;
        float z = y * y;
        m = fmaxf(m, z);
    }
    for (int c = 0; c < CC; ++c) {
        float y = row[c] * 10.0f;
        float z = y * y;
        row[c] = expf(z - m);
    }
    float r8[8];
    #pragma unroll
    for (int j = 0; j < 8; ++j) r8[j] = row[j];
    for (int i = 8; i < CC; i += 8) {
        #pragma unroll
        for (int j = 0; j < 8; ++j) r8[j] += row[i + j];
    }
    float s = ((r8[0] + r8[1]) + (r8[2] + r8[3])) + ((r8[4] + r8[5]) + (r8[6] + r8[7]));

    float score = 1.0f / s;
    for (int c = 0; c < CC; ++c) row[c] = row[c] * score;

    int gw = blockIdx.x * 128 + t;
    unsigned n = (unsigned)(gw & (NN - 1));
    keys[gw] = ((uint64_t)__float_as_uint(score) << 32)
             | (uint64_t)(0xFFFFFFFFu - n);

    __syncthreads();
    for (int i = t; i < 128 * CC; i += 128) {
        int r = i / CC, c = i - r * CC;
        probs[gbase + i] = buf[r * RSTRIDE + c];
    }
}

// ---------------------------------------------------------------------------
// K2a: partition + dynamic-size B-sort. One block (1024 thr) per batch
// (round-4 verified scan/scatter). og[] (over keys) = sorted index list.
// ---------------------------------------------------------------------------
__global__ __launch_bounds__(1024) void k_part(uint64_t* keys,
                                               int* __restrict__ nlist_g) {
    __shared__ uint64_t bbuf[BCAP];
    __shared__ int wsumA[16], wsumB[16];

    const int tid = threadIdx.x, lane = tid & 63, wv = tid >> 6;
    const int b = blockIdx.x;
    const uint64_t* kb = keys + (size_t)b * NN;
    int* og = (int*)(keys + (size_t)b * NN);

    uint64_t myk[4]; bool fa[4], fb[4];
    int asum = 0, bsum = 0;
    for (int k = 0; k < 4; ++k) {
        uint64_t key = kb[4 * tid + k]; myk[k] = key;
        unsigned hi = (unsigned)(key >> 32);
        fa[k] = (hi == 0x3F800000u);
        fb[k] = (__uint_as_float(hi) > CONF_T) && !fa[k];
        asum += fa[k] ? 1 : 0; bsum += fb[k] ? 1 : 0;
    }
    int ia = asum, ib = bsum;                       // wave-inclusive scans
    for (int off = 1; off < 64; off <<= 1) {
        int va = __shfl_up(ia, off), vb = __shfl_up(ib, off);
        if (lane >= off) { ia += va; ib += vb; }
    }
    if (lane == 63) { wsumA[wv] = ia; wsumB[wv] = ib; }
    __syncthreads();
    int baseA = 0, baseB = 0, cntA = 0, cntB = 0;
    for (int w2 = 0; w2 < 16; ++w2) {
        if (w2 < wv) { baseA += wsumA[w2]; baseB += wsumB[w2]; }
        cntA += wsumA[w2]; cntB += wsumB[w2];
    }
    int pA = baseA + (ia - asum);
    int pB = baseB + (ib - bsum);
    for (int k = 0; k < 4; ++k) {
        if (fa[k]) og[pA++] = 4 * tid + k;          // stable: idx order
        if (fb[k]) { if (pB < BCAP) bbuf[pB] = myk[k]; pB++; }
    }
    int cntBc = cntB < BCAP ? cntB : BCAP;
    int P2 = 64; while (P2 < cntBc) P2 <<= 1;       // dynamic sort size
    for (int i = tid; i < P2; i += 1024) if (i >= cntBc) bbuf[i] = 0;
    __syncthreads();

    for (unsigned k2 = 2; k2 <= (unsigned)P2; k2 <<= 1) {
        for (unsigned j = k2 >> 1; j > 0; j >>= 1) {
            for (unsigned i = tid; i < (unsigned)P2; i += 1024) {
                unsigned p = i ^ j;
                if (p > i) {
                    uint64_t va = bbuf[i], vb = bbuf[p];
                    bool desc = ((i & k2) == 0);
                    if (desc ? (va < vb) : (va > vb)) { bbuf[i] = vb; bbuf[p] = va; }
                }
            }
            __syncthreads();
        }
    }
    for (int i = tid; i < cntBc; i += 1024)
        og[cntA + i] = (int)(0xFFFFFFFFu - (unsigned)(bbuf[i] & 0xFFFFFFFFull));
    if (tid == 0) nlist_g[b] = cntA + cntBc;
}

// ---------------------------------------------------------------------------
// K2b: sorted corner/area arrays, one thread per (batch, sorted position).
// ---------------------------------------------------------------------------
__global__ __launch_bounds__(256) void k_corners(const float* __restrict__ boxes,
                                                 const uint64_t* __restrict__ keys,
                                                 const int* __restrict__ nlist_g,
                                                 float* __restrict__ y1s, float* __restrict__ x1s,
                                                 float* __restrict__ y2s, float* __restrict__ x2s,
                                                 float* __restrict__ ars) {
#pragma clang fp contract(off)
    int u = blockIdx.x * 256 + threadIdx.x;
    if (u >= BB * NN) return;
    int b = u >> 12, r = u & (NN - 1);
    if (r >= nlist_g[b]) return;
    size_t bN = (size_t)b * NN;
    const int* og = (const int*)(keys + bN);
    int o = og[r];
    float4 bv = ((const float4*)(boxes + bN * 4))[o];
    float y1 = fminf(bv.x, bv.z), y2 = fmaxf(bv.x, bv.z);
    float x1 = fminf(bv.y, bv.w), x2 = fmaxf(bv.y, bv.w);
    y1s[bN + r] = y1; x1s[bN + r] = x1;
    y2s[bN + r] = y2; x2s[bN + r] = x2;
    ars[bN + r] = (y2 - y1) * (x2 - x1);
}

// ---------------------------------------------------------------------------
// K3: head suppression-mask matrix. Block = (col-tile tj, batch b).
// ---------------------------------------------------------------------------
__global__ __launch_bounds__(1024) void k_iou(const float* __restrict__ y1s, const float* __restrict__ x1s,
                                              const float* __restrict__ y2s, const float* __restrict__ x2s,
                                              const float* __restrict__ ars,
                                              const int* __restrict__ nlist_g,
                                              uint64_t* __restrict__ mask) {
#pragma clang fp contract(off)
    __shared__ float ry1[HH], rx1[HH], ry2[HH], rx2[HH], rar[HH];
    int tj = blockIdx.x, b = blockIdx.y;
    int lane = threadIdx.x & 63, wv = threadIdx.x >> 6;
    int nl = nlist_g[b];
    int Hc = nl < HH ? nl : HH;
    int rmax = 64 * tj + 63; if (rmax > Hc) rmax = Hc;
    size_t bN = (size_t)b * NN;

    int j = 64 * tj + lane;
    bool jv = j < Hc;
    float cy1 = 0.f, cx1 = 0.f, cy2 = 0.f, cx2 = 0.f, car = 0.f;
    if (jv) { cy1 = y1s[bN + j]; cx1 = x1s[bN + j]; cy2 = y2s[bN + j]; cx2 = x2s[bN + j]; car = ars[bN + j]; }

    for (int i = threadIdx.x; i < rmax; i += 1024) {
        ry1[i] = y1s[bN + i]; rx1[i] = x1s[bN + i];
        ry2[i] = y2s[bN + i]; rx2[i] = x2s[bN + i];
        rar[i] = ars[bN + i];
    }
    __syncthreads();

    uint64_t* mrow = mask + (((size_t)b * HH) << 5) + tj;
    for (int i = wv; i < rmax; i += 16) {
        float a1 = ry1[i], c1 = rx1[i], a2 = ry2[i], c2 = rx2[i], aa = rar[i];
        float ih = fmaxf(0.f, fminf(cy2, a2) - fmaxf(cy1, a1));
        float iw = fmaxf(0.f, fminf(cx2, c2) - fmaxf(cx1, c1));
        float inter = ih * iw;
        float uni = (aa + car) - inter;
        bool s = jv && (j > i) && (inter > 0.f) && (inter / uni > IOU_T);
        uint64_t w = __ballot(s);
        if (lane == 0) mrow[(size_t)i << 5] = w;
    }
}

// ---------------------------------------------------------------------------
// K4: sweep. One block/batch; phase A = wave0 barrier-free register-bitmap
// sweep over head; phase B = all waves suppress tail vs head-keeps;
// phase C = wave0 walks surviving tail vs tail-keeps.
// ---------------------------------------------------------------------------
__global__ __launch_bounds__(1024) void k_sweep(const uint64_t* __restrict__ mask,
                                                const float* __restrict__ y1s, const float* __restrict__ x1s,
                                                const float* __restrict__ y2s, const float* __restrict__ x2s,
                                                const float* __restrict__ ars,
                                                const int* __restrict__ nlist_g,
                                                const uint64_t* __restrict__ keys,  // og overlay
                                                int* __restrict__ kidx_out,
                                                int* __restrict__ cnt_out) {
#pragma clang fp contract(off)
    __shared__ float kky1[MAXD], kkx1[MAXD], kky2[MAXD], kkx2[MAXD], kkar[MAXD];
    __shared__ int   kkidx[MAXD];
    __shared__ uint64_t tailw[HW];
    __shared__ int kA_s, ktot_s;

    int b = blockIdx.x;
    int tid = threadIdx.x, lane = tid & 63, wv = tid >> 6;
    int nl = nlist_g[b];
    int Hc = nl < HH ? nl : HH;
    size_t bN = (size_t)b * NN;
    const int* og = (const int*)(keys + bN);
    const uint64_t* mb = mask + (((size_t)b * HH) << 5);

    if (tid == 0) { kA_s = 0; ktot_s = 0; }
    for (int i = tid; i < HW; i += 1024) tailw[i] = 0;
    __syncthreads();

    // ---- phase A: wave0 head sweep ----
    if (wv == 0) {
        int lo = 64 * lane;
        uint64_t live;
        if (Hc <= lo) live = 0;
        else if (Hc >= lo + 64) live = ~0ull;
        else live = (1ull << (Hc - lo)) - 1ull;

        int kept = 0;
        while (kept < MAXD) {
            uint64_t bal = __ballot(live != 0);
            if (!bal) break;
            int fl = __ffsll((unsigned long long)bal) - 1;
            uint64_t w0 = __shfl(live, fl);
            int c = 64 * fl + (__ffsll((unsigned long long)w0) - 1);

            uint64_t rw = (lane < HW) ? mb[(((size_t)c) << 5) + lane] : 0;
            float ay1 = y1s[bN + c], ax1 = x1s[bN + c];
            float ay2 = y2s[bN + c], ax2 = x2s[bN + c];
            float aar = ars[bN + c];
            int oidx = og[c];

            int ct = c >> 6, cb = c & 63;
            if (lane < ct) rw = 0;
            else if (lane == ct) rw &= (cb == 63) ? 0ull : (~0ull << (cb + 1));
            live &= ~rw;
            if (lane == ct) live &= ~(1ull << cb);

            if (lane == 0) {
                kky1[kept] = ay1; kkx1[kept] = ax1;
                kky2[kept] = ay2; kkx2[kept] = ax2;
                kkar[kept] = aar; kkidx[kept] = oidx;
            }
            ++kept;
        }
        if (lane == 0) { kA_s = kept; ktot_s = kept; }
    }
    __syncthreads();

    // ---- phase B: parallel tail suppression vs head keeps ----
    int kA = kA_s;
    if (nl > HH && kA < MAXD) {
        for (int rep = 0; rep < 2; ++rep) {
            int c = HH + rep * 1024 + tid;
            bool sup = (c >= nl);
            float y1 = y1s[bN + c], x1 = x1s[bN + c];
            float y2 = y2s[bN + c], x2 = x2s[bN + c];
            float ar = ars[bN + c];
            for (int q = 0; q < kA; ++q) {
                float ih = fmaxf(0.f, fminf(y2, kky2[q]) - fmaxf(y1, kky1[q]));
                float iw = fmaxf(0.f, fminf(x2, kkx2[q]) - fmaxf(x1, kkx1[q]));
                float inter = ih * iw;
                float uni = (ar + kkar[q]) - inter;
                sup = sup || (inter > 0.f && inter / uni > IOU_T);
            }
            uint64_t balS = __ballot(!sup);
            if (lane == 0) tailw[rep * 16 + wv] = balS;
        }
    }
    __syncthreads();

    // ---- phase C: wave0 walks surviving tail candidates ----
    if (wv == 0 && nl > HH && kA < MAXD) {
        uint64_t tlive = (lane >= 32) ? tailw[lane - 32] : 0;
        int kept = kA;
        while (kept < MAXD) {
            uint64_t bal = __ballot(tlive != 0);
            if (!bal) break;
            int fl = __ffsll((unsigned long long)bal) - 1;
            uint64_t w0 = __shfl(tlive, fl);
            int bit = __ffsll((unsigned long long)w0) - 1;
            int c = HH + 64 * (fl - 32) + bit;
            if (lane == fl) tlive &= tlive - 1;

            float y1 = y1s[bN + c], x1 = x1s[bN + c];
            float y2 = y2s[bN + c], x2 = x2s[bN + c];
            float ar = ars[bN + c];
            bool hit = false;
            for (int q0 = kA; q0 < kept; q0 += 64) {
                int qi = q0 + lane;
                bool p = false;
                if (qi < kept) {
                    float ih = fmaxf(0.f, fminf(y2, kky2[qi]) - fmaxf(y1, kky1[qi]));
                    float iw = fmaxf(0.f, fminf(x2, kkx2[qi]) - fmaxf(x1, kkx1[qi]));
                    float inter = ih * iw;
                    float uni = (ar + kkar[qi]) - inter;
                    p = (inter > 0.f) && (inter / uni > IOU_T);
                }
                if (__ballot(p)) { hit = true; break; }
            }
            if (!hit) {
                if (lane == 0) {
                    kky1[kept] = y1; kkx1[kept] = x1;
                    kky2[kept] = y2; kkx2[kept] = x2;
                    kkar[kept] = ar; kkidx[kept] = og[c];
                }
                ++kept;
            }
        }
        if (lane == 0) ktot_s = kept;
    }
    __syncthreads();

    int kt = ktot_s;
    if (tid == 0) cnt_out[b] = kt;
    for (int i = tid; i < MAXD; i += 1024)
        kidx_out[b * MAXD + i] = (i < kt) ? kkidx[i] : 0;
}

// ---------------------------------------------------------------------------
// K5: wide parallel gather (unchanged).
// ---------------------------------------------------------------------------
__global__ __launch_bounds__(256) void k_gather(const float* __restrict__ boxes,
                                                const float* __restrict__ probs,
                                                const int* __restrict__ kidx,
                                                const int* __restrict__ cnt,
                                                float* __restrict__ out_box,
                                                float* __restrict__ out_cls) {
    int u = blockIdx.x * 256 + threadIdx.x;
    if (u >= BB * PER_B) return;
    int b = u / PER_B;
    int r = u - b * PER_B;
    int count = cnt[b];
    float val = 0.0f;
    if (r < MAXD * 4) {
        int t = r >> 2, e = r & 3;
        if (t < count) {
            int idx = kidx[b * MAXD + t];
            val = boxes[((size_t)b * NN + idx) * 4 + e];
        }
        out_box[(size_t)b * MAXD * 4 + r] = val;
    } else {
        int q = r - MAXD * 4;
        int t = q / CC, c = q - t * CC;
        if (t < count) {
            int idx = kidx[b * MAXD + t];
            val = probs[((size_t)b * NN + idx) * CC + c];
        }
        out_cls[(size_t)b * MAXD * CC + q] = val;
    }
}

// ---------------------------------------------------------------------------
// FALLBACK (ws too small): round-4 fused k_nms — verified passing.
// ---------------------------------------------------------------------------
__global__ __launch_bounds__(1024) void k_nms_fb(uint64_t* keys,
                                                 const float* __restrict__ boxes,
                                                 int* __restrict__ kidx_out,
                                                 int* __restrict__ cnt_out) {
#pragma clang fp contract(off)
    __shared__ float sy1[SEGSZ], sx1[SEGSZ], sy2[SEGSZ], sx2[SEGSZ];
    __shared__ int   soidx[SEGSZ];
    __shared__ uint64_t bbuf[BCAP];
    __shared__ uint64_t sup[NWORDS];
    __shared__ float ky1[MAXD], kx1[MAXD], ky2[MAXD], kx2[MAXD], kar[MAXD];
    __shared__ int   keptidx[MAXD];
    __shared__ int   wsumA[16], wsumB[16];
    __shared__ int   keptcnt_s, ctrl_s, seg_s;

    const int tid = threadIdx.x, lane = tid & 63, wv = tid >> 6;
    const int b = blockIdx.x;
    const uint64_t* kb = keys + (size_t)b * NN;
    const float* bxp = boxes + (size_t)b * NN * 4;
    int* og = (int*)(keys + (size_t)b * NN);

    uint64_t myk[4]; bool fa[4], fb[4];
    int asum = 0, bsum = 0;
    for (int k = 0; k < 4; ++k) {
        uint64_t key = kb[4 * tid + k]; myk[k] = key;
        unsigned hi = (unsigned)(key >> 32);
        fa[k] = (hi == 0x3F800000u);
        fb[k] = (__uint_as_float(hi) > CONF_T) && !fa[k];
        asum += fa[k] ? 1 : 0; bsum += fb[k] ? 1 : 0;
    }
    int ia = asum, ib = bsum;
    for (int off = 1; off < 64; off <<= 1) {
        int va = __shfl_up(ia, off), vb = __shfl_up(ib, off);
        if (lane >= off) { ia += va; ib += vb; }
    }
    if (lane == 63) { wsumA[wv] = ia; wsumB[wv] = ib; }
    __syncthreads();
    int baseA = 0, baseB = 0, cntA = 0, cntB = 0;
    for (int w2 = 0; w2 < 16; ++w2) {
        if (w2 < wv) { baseA += wsumA[w2]; baseB += wsumB[w2]; }
        cntA += wsumA[w2]; cntB += wsumB[w2];
    }
    int pA = baseA + (ia - asum);
    int pB = baseB + (ib - bsum);
    for (int k = 0; k < 4; ++k) {
        if (fa[k]) og[pA++] = 4 * tid + k;
        if (fb[k]) { if (pB < BCAP) bbuf[pB] = myk[k]; pB++; }
    }
    int cntBc = cntB < BCAP ? cntB : BCAP;
    int nlist = cntA + cntBc;
    if (tid == 0) { keptcnt_s = 0; seg_s = 0; }
    for (int i = tid; i < BCAP; i += 1024) if (i >= cntB) bbuf[i] = 0;
    __syncthreads();

    for (unsigned k2 = 2; k2 <= BCAP; k2 <<= 1) {
        for (unsigned j = k2 >> 1; j > 0; j >>= 1) {
            for (unsigned i = tid; i < BCAP; i += 1024) {
                unsigned p = i ^ j;
                if (p > i) {
                    uint64_t va = bbuf[i], vb = bbuf[p];
                    bool desc = ((i & k2) == 0);
                    if (desc ? (va < vb) : (va > vb)) { bbuf[i] = vb; bbuf[p] = va; }
                }
            }
            __syncthreads();
        }
    }
    for (int i = tid; i < cntBc; i += 1024)
        og[cntA + i] = (int)(0xFFFFFFFFu - (unsigned)(bbuf[i] & 0xFFFFFFFFull));
    if (tid < NWORDS) {
        int lo = tid * 64;
        uint64_t mm;
        if (nlist <= lo) mm = ~0ull;
        else if (nlist >= lo + 64) mm = 0ull;
        else mm = (~0ull) << (nlist - lo);
        sup[tid] = mm;
    }
    __syncthreads();

    for (int i = tid; i < SEGSZ; i += 1024) {
        if (i < nlist) {
            int o = og[i];
            soidx[i] = o;
            const float* bp = bxp + (size_t)o * 4;
            float b0 = bp[0], b1 = bp[1], b2 = bp[2], b3 = bp[3];
            sy1[i] = fminf(b0, b2); sy2[i] = fmaxf(b0, b2);
            sx1[i] = fminf(b1, b3); sx2[i] = fmaxf(b1, b3);
        }
    }
    __syncthreads();

    int curw = 0, segr = 0;
    while (true) {
        if (tid == 0) {
            int code = -1;
            for (;;) {
                int wend = (segr + 1) * (SEGSZ / 64);
                if (curw >= wend) {
                    if (segr == 0 && nlist > SEGSZ) {
                        code = -2; segr = 1; seg_s = 1; curw = SEGSZ / 64;
                    } else code = -1;
                    break;
                }
                uint64_t live = ~sup[curw];
                if (live) {
                    int j = __ffsll((unsigned long long)live) - 1;
                    int sel = curw * 64 + j;
                    int li = sel - segr * SEGSZ;
                    int kc = keptcnt_s;
                    keptidx[kc] = soidx[li];
                    ky1[kc] = sy1[li]; kx1[kc] = sx1[li];
                    ky2[kc] = sy2[li]; kx2[kc] = sx2[li];
                    kar[kc] = (sy2[li] - sy1[li]) * (sx2[li] - sx1[li]);
                    keptcnt_s = kc + 1;
                    sup[curw] |= (1ull << j);
                    code = (kc + 1 >= MAXD) ? -1 : sel;
                    break;
                }
                ++curw;
            }
            ctrl_s = code;
        }
        __syncthreads();
        int c = ctrl_s;
        if (c == -1) break;

        if (c == -2) {
            for (int i = tid; i < SEGSZ; i += 1024) {
                int gi = SEGSZ + i;
                if (gi < nlist) {
                    int o = og[gi];
                    soidx[i] = o;
                    const float* bp = bxp + (size_t)o * 4;
                    float b0 = bp[0], b1 = bp[1], b2 = bp[2], b3 = bp[3];
                    sy1[i] = fminf(b0, b2); sy2[i] = fmaxf(b0, b2);
                    sx1[i] = fminf(b1, b3); sx2[i] = fmaxf(b1, b3);
                }
            }
            __syncthreads();
            int kc = keptcnt_s;
            for (int k = 0; k < 2; ++k) {
                int li = tid + k * 1024;
                float y1 = sy1[li], y2 = sy2[li], x1 = sx1[li], x2 = sx2[li];
                float ar = (y2 - y1) * (x2 - x1);
                bool s = false;
                for (int q = 0; q < kc; ++q) {
                    float ih = fmaxf(0.f, fminf(y2, ky2[q]) - fmaxf(y1, ky1[q]));
                    float iw = fmaxf(0.f, fminf(x2, kx2[q]) - fmaxf(x1, kx1[q]));
                    float inter = ih * iw;
                    float uni = (ar + kar[q]) - inter;
                    s = s || (inter > 0.f && inter / uni > IOU_T);
                }
                uint64_t bal = __ballot(s);
                if (lane == 0 && bal) {
                    int word = (SEGSZ + k * 1024 + wv * 64) >> 6;
                    sup[word] |= bal;
                }
            }
            __syncthreads();
            continue;
        }

        int sg = seg_s;
        int cl = c - sg * SEGSZ;
        float cy1 = sy1[cl], cy2 = sy2[cl], cx1 = sx1[cl], cx2 = sx2[cl];
        float car = (cy2 - cy1) * (cx2 - cx1);
        for (int k = 0; k < 2; ++k) {
            int li = tid + k * 1024;
            float y1 = sy1[li], y2 = sy2[li], x1 = sx1[li], x2 = sx2[li];
            float ar = (y2 - y1) * (x2 - x1);
            float ih = fmaxf(0.f, fminf(y2, cy2) - fmaxf(y1, cy1));
            float iw = fmaxf(0.f, fminf(x2, cx2) - fmaxf(x1, cx1));
            float inter = ih * iw;
            float uni = (ar + car) - inter;
            bool s = (inter > 0.f) && (inter / uni > IOU_T);
            uint64_t bal = __ballot(s);
            if (lane == 0 && bal) {
                int word = (sg * SEGSZ + k * 1024 + wv * 64) >> 6;
                sup[word] |= bal;
            }
        }
        __syncthreads();
    }

    if (tid == 0) cnt_out[b] = keptcnt_s;
    for (int i = tid; i < MAXD; i += 1024)
        kidx_out[b * MAXD + i] = (i < keptcnt_s) ? keptidx[i] : 0;
}

extern "C" void kernel_launch(void* const* d_in, const int* in_sizes, int n_in,
                              void* d_out, int out_size, void* d_ws, size_t ws_size,
                              hipStream_t stream) {
    const float* boxes = (const float*)d_in[0];   // [B,N,4]
    const float* cls   = (const float*)d_in[1];   // [B,N,C]
    float* out = (float*)d_out;
    float* out_box = out;                                                  // [B,100,4]
    float* out_cls = out + (size_t)BB * MAXD * 4;                          // [B,100,80]
    float* probs   = out + (size_t)BB * MAXD * 4 + (size_t)BB * MAXD * CC; // [B,N,80]

    char* ws = (char*)d_ws;
    uint64_t* keys = (uint64_t*)(ws + WS_KEYS);

    k_softmax<<<(BB * NN) / 128, 128, 0, stream>>>(cls, probs, keys);

    if (ws_size >= (size_t)WS_NEED) {
        float* y1s = (float*)(ws + WS_Y1S);
        float* x1s = (float*)(ws + WS_X1S);
        float* y2s = (float*)(ws + WS_Y2S);
        float* x2s = (float*)(ws + WS_X2S);
        float* ars = (float*)(ws + WS_ARS);
        int* nlist = (int*)(ws + WS_NLIST);
        int* kidx  = (int*)(ws + WS_KIDX);
        int* cnt   = (int*)(ws + WS_CNT);
        uint64_t* mask = (uint64_t*)(ws + WS_MASK);

        k_part<<<BB, 1024, 0, stream>>>(keys, nlist);
        k_corners<<<(BB * NN) / 256, 256, 0, stream>>>(boxes, keys, nlist,
                                                       y1s, x1s, y2s, x2s, ars);
        k_iou<<<dim3(HW, BB), 1024, 0, stream>>>(y1s, x1s, y2s, x2s, ars, nlist, mask);
        k_sweep<<<BB, 1024, 0, stream>>>(mask, y1s, x1s, y2s, x2s, ars, nlist,
                                         keys, kidx, cnt);
        k_gather<<<(BB * PER_B + 255) / 256, 256, 0, stream>>>(boxes, probs, kidx, cnt,
                                                               out_box, out_cls);
    } else {
        int* kidx = (int*)(ws + (size_t)BB * NN * sizeof(uint64_t));
        int* cnt  = kidx + BB * MAXD;
        k_nms_fb<<<BB, 1024, 0, stream>>>(keys, boxes, kidx, cnt);
        k_gather<<<(BB * PER_B + 255) / 256, 256, 0, stream>>>(boxes, probs, kidx, cnt,
                                                               out_box, out_cls);
    }
}

// Round 7
// 200.216 us; speedup vs baseline: 1.4321x; 1.0949x over previous
//
#include <hip/hip_runtime.h>
#include <cstdint>
#include <cstddef>

#define BB 16
#define NN 4096
#define CC 80
#define MAXD 100
#define IOU_T 0.5f
#define CONF_T 0.5f
#define RSTRIDE 81
#define PER_B (MAXD * 4 + MAXD * CC)   // 8400 output elems per batch
#define NWORDS (NN / 64)
#define BCAP 2048
#define SEGSZ 2048
#define HH 2048                        // head size for mask matrix
#define HW 32                          // head words (HH/64)

// ---- workspace layout (fast path) ----
#define WS_KEYS   0x000000             // [B*N] u64 (og int list overlays)
#define WS_Y1S    0x080000             // [B*N] f32 each
#define WS_X1S    0x0C0000
#define WS_Y2S    0x100000
#define WS_X2S    0x140000
#define WS_ARS    0x180000
#define WS_NLIST  0x1C0000             // [B] int
#define WS_KIDX   0x1C0100             // [B*100] int
#define WS_CNT    0x1C2000             // [B] int
#define WS_MASK   0x200000             // [B*HH*HW] u64 = 8 MB
#define WS_NEED   0xA00000             // 10.5 MB

// ---------------------------------------------------------------------------
// K1: softmax of (10x)^2 per row, one THREAD per row, 128 rows/block.
// numpy pairwise-8 sum DAG for s (bitwise == np); score = IEEE fl(1/s).
// ---------------------------------------------------------------------------
__global__ __launch_bounds__(128) void k_softmax(const float* __restrict__ cls_in,
                                                 float* __restrict__ probs,
                                                 uint64_t* __restrict__ keys) {
#pragma clang fp contract(off)
    __shared__ float buf[128 * RSTRIDE];
    int t = threadIdx.x;
    size_t gbase = (size_t)blockIdx.x * 128 * CC;

    for (int i = t; i < 128 * CC; i += 128) {
        int r = i / CC, c = i - r * CC;
        buf[r * RSTRIDE + c] = cls_in[gbase + i];
    }
    __syncthreads();

    float* row = buf + t * RSTRIDE;

    float m = -3.402823466e+38f;
    for (int c = 0; c < CC; ++c) {
        float y = row[c] * 10.0f;
        float z = y * y;
        m = fmaxf(m, z);
    }
    for (int c = 0; c < CC; ++c) {
        float y = row[c] * 10.0f;
        float z = y * y;
        row[c] = expf(z - m);
    }
    float r8[8];
    #pragma unroll
    for (int j = 0; j < 8; ++j) r8[j] = row[j];
    for (int i = 8; i < CC; i += 8) {
        #pragma unroll
        for (int j = 0; j < 8; ++j) r8[j] += row[i + j];
    }
    float s = ((r8[0] + r8[1]) + (r8[2] + r8[3])) + ((r8[4] + r8[5]) + (r8[6] + r8[7]));

    float score = 1.0f / s;
    for (int c = 0; c < CC; ++c) row[c] = row[c] * score;

    int gw = blockIdx.x * 128 + t;
    unsigned n = (unsigned)(gw & (NN - 1));
    keys[gw] = ((uint64_t)__float_as_uint(score) << 32)
             | (uint64_t)(0xFFFFFFFFu - n);

    __syncthreads();
    for (int i = t; i < 128 * CC; i += 128) {
        int r = i / CC, c = i - r * CC;
        probs[gbase + i] = buf[r * RSTRIDE + c];
    }
}

// ---------------------------------------------------------------------------
// K2: partition + dynamic-size B-sort + fused sorted-corner build.
// One block (1024 thr) per batch; blockIdx.x = b -> XCD b%8 (locality anchor).
// ---------------------------------------------------------------------------
__global__ __launch_bounds__(1024) void k_part(uint64_t* keys,
                                               const float* __restrict__ boxes,
                                               float* __restrict__ y1s, float* __restrict__ x1s,
                                               float* __restrict__ y2s, float* __restrict__ x2s,
                                               float* __restrict__ ars,
                                               int* __restrict__ nlist_g) {
#pragma clang fp contract(off)
    __shared__ uint64_t bbuf[BCAP];
    __shared__ int wsumA[16], wsumB[16];

    const int tid = threadIdx.x, lane = tid & 63, wv = tid >> 6;
    const int b = blockIdx.x;
    const uint64_t* kb = keys + (size_t)b * NN;
    int* og = (int*)(keys + (size_t)b * NN);
    size_t bN = (size_t)b * NN;

    uint64_t myk[4]; bool fa[4], fb[4];
    int asum = 0, bsum = 0;
    for (int k = 0; k < 4; ++k) {
        uint64_t key = kb[4 * tid + k]; myk[k] = key;   // all reads precede barrier
        unsigned hi = (unsigned)(key >> 32);
        fa[k] = (hi == 0x3F800000u);
        fb[k] = (__uint_as_float(hi) > CONF_T) && !fa[k];
        asum += fa[k] ? 1 : 0; bsum += fb[k] ? 1 : 0;
    }
    int ia = asum, ib = bsum;                       // wave-inclusive scans
    for (int off = 1; off < 64; off <<= 1) {
        int va = __shfl_up(ia, off), vb = __shfl_up(ib, off);
        if (lane >= off) { ia += va; ib += vb; }
    }
    if (lane == 63) { wsumA[wv] = ia; wsumB[wv] = ib; }
    __syncthreads();
    int baseA = 0, baseB = 0, cntA = 0, cntB = 0;
    for (int w2 = 0; w2 < 16; ++w2) {
        if (w2 < wv) { baseA += wsumA[w2]; baseB += wsumB[w2]; }
        cntA += wsumA[w2]; cntB += wsumB[w2];
    }
    int pA = baseA + (ia - asum);
    int pB = baseB + (ib - bsum);
    for (int k = 0; k < 4; ++k) {
        if (fa[k]) og[pA++] = 4 * tid + k;          // stable: idx order
        if (fb[k]) { if (pB < BCAP) bbuf[pB] = myk[k]; pB++; }
    }
    int cntBc = cntB < BCAP ? cntB : BCAP;
    int P2 = 64; while (P2 < cntBc) P2 <<= 1;       // dynamic sort size
    for (int i = tid; i < P2; i += 1024) if (i >= cntBc) bbuf[i] = 0;
    __syncthreads();

    for (unsigned k2 = 2; k2 <= (unsigned)P2; k2 <<= 1) {
        for (unsigned j = k2 >> 1; j > 0; j >>= 1) {
            for (unsigned i = tid; i < (unsigned)P2; i += 1024) {
                unsigned p = i ^ j;
                if (p > i) {
                    uint64_t va = bbuf[i], vb = bbuf[p];
                    bool desc = ((i & k2) == 0);
                    if (desc ? (va < vb) : (va > vb)) { bbuf[i] = vb; bbuf[p] = va; }
                }
            }
            __syncthreads();
        }
    }
    for (int i = tid; i < cntBc; i += 1024)
        og[cntA + i] = (int)(0xFFFFFFFFu - (unsigned)(bbuf[i] & 0xFFFFFFFFull));
    int nl = cntA + cntBc;
    if (tid == 0) nlist_g[b] = nl;
    __syncthreads();   // og complete & visible block-wide (write-through L1)

    // fused sorted corner/area build (og is L2-hot)
    const float* bxp = boxes + bN * 4;
    for (int i = tid; i < nl; i += 1024) {
        int o = og[i];
        float4 bv = ((const float4*)bxp)[o];
        float y1 = fminf(bv.x, bv.z), y2 = fmaxf(bv.x, bv.z);
        float x1 = fminf(bv.y, bv.w), x2 = fmaxf(bv.y, bv.w);
        y1s[bN + i] = y1; x1s[bN + i] = x1;
        y2s[bN + i] = y2; x2s[bN + i] = x2;
        ars[bN + i] = (y2 - y1) * (x2 - x1);
    }
}

// ---------------------------------------------------------------------------
// K3 v2: head suppression-mask matrix, ROW-TILE blocks + LDS-staged output.
// Block x = ti*16 + b  (so XCD = x%8 = b%8, matching k_part/k_sweep).
// Stage all 2048 col corners in LDS; each wave computes 4 rows x (32-ti)
// words into om[64][32]; final contiguous 16 KB coalesced store (fixes the
// round-6 partial-line RMW write bottleneck: 8B stores @256B stride).
// ---------------------------------------------------------------------------
__global__ __launch_bounds__(1024) void k_iou(const float* __restrict__ y1s, const float* __restrict__ x1s,
                                              const float* __restrict__ y2s, const float* __restrict__ x2s,
                                              const float* __restrict__ ars,
                                              const int* __restrict__ nlist_g,
                                              uint64_t* __restrict__ mask) {
#pragma clang fp contract(off)
    __shared__ float cy1[HH], cx1[HH], cy2[HH], cx2[HH], cas[HH];
    __shared__ uint64_t om[64 * HW];
    int x = blockIdx.x;
    int b = x & 15, ti = x >> 4;
    int tid = threadIdx.x, lane = tid & 63, wv = tid >> 6;
    int nl = nlist_g[b];
    int Hc = nl < HH ? nl : HH;
    size_t bN = (size_t)b * NN;

    for (int i = tid; i < HH; i += 1024) {
        bool v = i < Hc;
        cy1[i] = v ? y1s[bN + i] : 0.f;
        cx1[i] = v ? x1s[bN + i] : 0.f;
        cy2[i] = v ? y2s[bN + i] : 0.f;
        cx2[i] = v ? x2s[bN + i] : 0.f;
        cas[i] = v ? ars[bN + i] : 0.f;
    }
    for (int i = tid; i < 64 * HW; i += 1024) om[i] = 0;
    __syncthreads();

    for (int r = wv; r < 64; r += 16) {
        int i = ti * 64 + r;
        if (i >= Hc) continue;
        float a1 = cy1[i], a3 = cx1[i], a2 = cy2[i], a4 = cx2[i], aa = cas[i];
        for (int tj = ti; tj < HW; ++tj) {
            int j = tj * 64 + lane;
            float ih = fmaxf(0.f, fminf(a2, cy2[j]) - fmaxf(a1, cy1[j]));
            float iw = fmaxf(0.f, fminf(a4, cx2[j]) - fmaxf(a3, cx1[j]));
            float inter = ih * iw;
            float uni = (aa + cas[j]) - inter;
            bool s = (j < Hc) && (j > i) && (inter > 0.f) && (inter / uni > IOU_T);
            uint64_t w = __ballot(s);
            if (lane == 0) om[r * HW + tj] = w;
        }
    }
    __syncthreads();

    uint64_t* mdst = mask + ((size_t)b * HH + (size_t)ti * 64) * HW;
    for (int i = tid; i < 64 * HW; i += 1024) mdst[i] = om[i];
}

// ---------------------------------------------------------------------------
// K4: sweep (unchanged, verified). Row-major mask layout preserved.
// ---------------------------------------------------------------------------
__global__ __launch_bounds__(1024) void k_sweep(const uint64_t* __restrict__ mask,
                                                const float* __restrict__ y1s, const float* __restrict__ x1s,
                                                const float* __restrict__ y2s, const float* __restrict__ x2s,
                                                const float* __restrict__ ars,
                                                const int* __restrict__ nlist_g,
                                                const uint64_t* __restrict__ keys,  // og overlay
                                                int* __restrict__ kidx_out,
                                                int* __restrict__ cnt_out) {
#pragma clang fp contract(off)
    __shared__ float kky1[MAXD], kkx1[MAXD], kky2[MAXD], kkx2[MAXD], kkar[MAXD];
    __shared__ int   kkidx[MAXD];
    __shared__ uint64_t tailw[HW];
    __shared__ int kA_s, ktot_s;

    int b = blockIdx.x;
    int tid = threadIdx.x, lane = tid & 63, wv = tid >> 6;
    int nl = nlist_g[b];
    int Hc = nl < HH ? nl : HH;
    size_t bN = (size_t)b * NN;
    const int* og = (const int*)(keys + bN);
    const uint64_t* mb = mask + (((size_t)b * HH) << 5);

    if (tid == 0) { kA_s = 0; ktot_s = 0; }
    for (int i = tid; i < HW; i += 1024) tailw[i] = 0;
    __syncthreads();

    // ---- phase A: wave0 head sweep ----
    if (wv == 0) {
        int lo = 64 * lane;
        uint64_t live;
        if (Hc <= lo) live = 0;
        else if (Hc >= lo + 64) live = ~0ull;
        else live = (1ull << (Hc - lo)) - 1ull;

        int kept = 0;
        while (kept < MAXD) {
            uint64_t bal = __ballot(live != 0);
            if (!bal) break;
            int fl = __ffsll((unsigned long long)bal) - 1;
            uint64_t w0 = __shfl(live, fl);
            int c = 64 * fl + (__ffsll((unsigned long long)w0) - 1);

            uint64_t rw = (lane < HW) ? mb[(((size_t)c) << 5) + lane] : 0;
            float ay1 = y1s[bN + c], ax1 = x1s[bN + c];
            float ay2 = y2s[bN + c], ax2 = x2s[bN + c];
            float aar = ars[bN + c];
            int oidx = og[c];

            int ct = c >> 6, cb = c & 63;
            if (lane < ct) rw = 0;
            else if (lane == ct) rw &= (cb == 63) ? 0ull : (~0ull << (cb + 1));
            live &= ~rw;
            if (lane == ct) live &= ~(1ull << cb);

            if (lane == 0) {
                kky1[kept] = ay1; kkx1[kept] = ax1;
                kky2[kept] = ay2; kkx2[kept] = ax2;
                kkar[kept] = aar; kkidx[kept] = oidx;
            }
            ++kept;
        }
        if (lane == 0) { kA_s = kept; ktot_s = kept; }
    }
    __syncthreads();

    // ---- phase B: parallel tail suppression vs head keeps ----
    int kA = kA_s;
    if (nl > HH && kA < MAXD) {
        for (int rep = 0; rep < 2; ++rep) {
            int c = HH + rep * 1024 + tid;
            bool sup = (c >= nl);
            float y1 = y1s[bN + c], x1 = x1s[bN + c];
            float y2 = y2s[bN + c], x2 = x2s[bN + c];
            float ar = ars[bN + c];
            for (int q = 0; q < kA; ++q) {
                float ih = fmaxf(0.f, fminf(y2, kky2[q]) - fmaxf(y1, kky1[q]));
                float iw = fmaxf(0.f, fminf(x2, kkx2[q]) - fmaxf(x1, kkx1[q]));
                float inter = ih * iw;
                float uni = (ar + kkar[q]) - inter;
                sup = sup || (inter > 0.f && inter / uni > IOU_T);
            }
            uint64_t balS = __ballot(!sup);
            if (lane == 0) tailw[rep * 16 + wv] = balS;
        }
    }
    __syncthreads();

    // ---- phase C: wave0 walks surviving tail candidates ----
    if (wv == 0 && nl > HH && kA < MAXD) {
        uint64_t tlive = (lane >= 32) ? tailw[lane - 32] : 0;
        int kept = kA;
        while (kept < MAXD) {
            uint64_t bal = __ballot(tlive != 0);
            if (!bal) break;
            int fl = __ffsll((unsigned long long)bal) - 1;
            uint64_t w0 = __shfl(tlive, fl);
            int bit = __ffsll((unsigned long long)w0) - 1;
            int c = HH + 64 * (fl - 32) + bit;
            if (lane == fl) tlive &= tlive - 1;

            float y1 = y1s[bN + c], x1 = x1s[bN + c];
            float y2 = y2s[bN + c], x2 = x2s[bN + c];
            float ar = ars[bN + c];
            bool hit = false;
            for (int q0 = kA; q0 < kept; q0 += 64) {
                int qi = q0 + lane;
                bool p = false;
                if (qi < kept) {
                    float ih = fmaxf(0.f, fminf(y2, kky2[qi]) - fmaxf(y1, kky1[qi]));
                    float iw = fmaxf(0.f, fminf(x2, kkx2[qi]) - fmaxf(x1, kkx1[qi]));
                    float inter = ih * iw;
                    float uni = (ar + kkar[qi]) - inter;
                    p = (inter > 0.f) && (inter / uni > IOU_T);
                }
                if (__ballot(p)) { hit = true; break; }
            }
            if (!hit) {
                if (lane == 0) {
                    kky1[kept] = y1; kkx1[kept] = x1;
                    kky2[kept] = y2; kkx2[kept] = x2;
                    kkar[kept] = ar; kkidx[kept] = og[c];
                }
                ++kept;
            }
        }
        if (lane == 0) ktot_s = kept;
    }
    __syncthreads();

    int kt = ktot_s;
    if (tid == 0) cnt_out[b] = kt;
    for (int i = tid; i < MAXD; i += 1024)
        kidx_out[b * MAXD + i] = (i < kt) ? kkidx[i] : 0;
}

// ---------------------------------------------------------------------------
// K5: wide parallel gather (unchanged).
// ---------------------------------------------------------------------------
__global__ __launch_bounds__(256) void k_gather(const float* __restrict__ boxes,
                                                const float* __restrict__ probs,
                                                const int* __restrict__ kidx,
                                                const int* __restrict__ cnt,
                                                float* __restrict__ out_box,
                                                float* __restrict__ out_cls) {
    int u = blockIdx.x * 256 + threadIdx.x;
    if (u >= BB * PER_B) return;
    int b = u / PER_B;
    int r = u - b * PER_B;
    int count = cnt[b];
    float val = 0.0f;
    if (r < MAXD * 4) {
        int t = r >> 2, e = r & 3;
        if (t < count) {
            int idx = kidx[b * MAXD + t];
            val = boxes[((size_t)b * NN + idx) * 4 + e];
        }
        out_box[(size_t)b * MAXD * 4 + r] = val;
    } else {
        int q = r - MAXD * 4;
        int t = q / CC, c = q - t * CC;
        if (t < count) {
            int idx = kidx[b * MAXD + t];
            val = probs[((size_t)b * NN + idx) * CC + c];
        }
        out_cls[(size_t)b * MAXD * CC + q] = val;
    }
}

// ---------------------------------------------------------------------------
// FALLBACK (ws too small): round-4 fused k_nms — verified passing.
// ---------------------------------------------------------------------------
__global__ __launch_bounds__(1024) void k_nms_fb(uint64_t* keys,
                                                 const float* __restrict__ boxes,
                                                 int* __restrict__ kidx_out,
                                                 int* __restrict__ cnt_out) {
#pragma clang fp contract(off)
    __shared__ float sy1[SEGSZ], sx1[SEGSZ], sy2[SEGSZ], sx2[SEGSZ];
    __shared__ int   soidx[SEGSZ];
    __shared__ uint64_t bbuf[BCAP];
    __shared__ uint64_t sup[NWORDS];
    __shared__ float ky1[MAXD], kx1[MAXD], ky2[MAXD], kx2[MAXD], kar[MAXD];
    __shared__ int   keptidx[MAXD];
    __shared__ int   wsumA[16], wsumB[16];
    __shared__ int   keptcnt_s, ctrl_s, seg_s;

    const int tid = threadIdx.x, lane = tid & 63, wv = tid >> 6;
    const int b = blockIdx.x;
    const uint64_t* kb = keys + (size_t)b * NN;
    const float* bxp = boxes + (size_t)b * NN * 4;
    int* og = (int*)(keys + (size_t)b * NN);

    uint64_t myk[4]; bool fa[4], fb[4];
    int asum = 0, bsum = 0;
    for (int k = 0; k < 4; ++k) {
        uint64_t key = kb[4 * tid + k]; myk[k] = key;
        unsigned hi = (unsigned)(key >> 32);
        fa[k] = (hi == 0x3F800000u);
        fb[k] = (__uint_as_float(hi) > CONF_T) && !fa[k];
        asum += fa[k] ? 1 : 0; bsum += fb[k] ? 1 : 0;
    }
    int ia = asum, ib = bsum;
    for (int off = 1; off < 64; off <<= 1) {
        int va = __shfl_up(ia, off), vb = __shfl_up(ib, off);
        if (lane >= off) { ia += va; ib += vb; }
    }
    if (lane == 63) { wsumA[wv] = ia; wsumB[wv] = ib; }
    __syncthreads();
    int baseA = 0, baseB = 0, cntA = 0, cntB = 0;
    for (int w2 = 0; w2 < 16; ++w2) {
        if (w2 < wv) { baseA += wsumA[w2]; baseB += wsumB[w2]; }
        cntA += wsumA[w2]; cntB += wsumB[w2];
    }
    int pA = baseA + (ia - asum);
    int pB = baseB + (ib - bsum);
    for (int k = 0; k < 4; ++k) {
        if (fa[k]) og[pA++] = 4 * tid + k;
        if (fb[k]) { if (pB < BCAP) bbuf[pB] = myk[k]; pB++; }
    }
    int cntBc = cntB < BCAP ? cntB : BCAP;
    int nlist = cntA + cntBc;
    if (tid == 0) { keptcnt_s = 0; seg_s = 0; }
    for (int i = tid; i < BCAP; i += 1024) if (i >= cntB) bbuf[i] = 0;
    __syncthreads();

    for (unsigned k2 = 2; k2 <= BCAP; k2 <<= 1) {
        for (unsigned j = k2 >> 1; j > 0; j >>= 1) {
            for (unsigned i = tid; i < BCAP; i += 1024) {
                unsigned p = i ^ j;
                if (p > i) {
                    uint64_t va = bbuf[i], vb = bbuf[p];
                    bool desc = ((i & k2) == 0);
                    if (desc ? (va < vb) : (va > vb)) { bbuf[i] = vb; bbuf[p] = va; }
                }
            }
            __syncthreads();
        }
    }
    for (int i = tid; i < cntBc; i += 1024)
        og[cntA + i] = (int)(0xFFFFFFFFu - (unsigned)(bbuf[i] & 0xFFFFFFFFull));
    if (tid < NWORDS) {
        int lo = tid * 64;
        uint64_t mm;
        if (nlist <= lo) mm = ~0ull;
        else if (nlist >= lo + 64) mm = 0ull;
        else mm = (~0ull) << (nlist - lo);
        sup[tid] = mm;
    }
    __syncthreads();

    for (int i = tid; i < SEGSZ; i += 1024) {
        if (i < nlist) {
            int o = og[i];
            soidx[i] = o;
            const float* bp = bxp + (size_t)o * 4;
            float b0 = bp[0], b1 = bp[1], b2 = bp[2], b3 = bp[3];
            sy1[i] = fminf(b0, b2); sy2[i] = fmaxf(b0, b2);
            sx1[i] = fminf(b1, b3); sx2[i] = fmaxf(b1, b3);
        }
    }
    __syncthreads();

    int curw = 0, segr = 0;
    while (true) {
        if (tid == 0) {
            int code = -1;
            for (;;) {
                int wend = (segr + 1) * (SEGSZ / 64);
                if (curw >= wend) {
                    if (segr == 0 && nlist > SEGSZ) {
                        code = -2; segr = 1; seg_s = 1; curw = SEGSZ / 64;
                    } else code = -1;
                    break;
                }
                uint64_t live = ~sup[curw];
                if (live) {
                    int j = __ffsll((unsigned long long)live) - 1;
                    int sel = curw * 64 + j;
                    int li = sel - segr * SEGSZ;
                    int kc = keptcnt_s;
                    keptidx[kc] = soidx[li];
                    ky1[kc] = sy1[li]; kx1[kc] = sx1[li];
                    ky2[kc] = sy2[li]; kx2[kc] = sx2[li];
                    kar[kc] = (sy2[li] - sy1[li]) * (sx2[li] - sx1[li]);
                    keptcnt_s = kc + 1;
                    sup[curw] |= (1ull << j);
                    code = (kc + 1 >= MAXD) ? -1 : sel;
                    break;
                }
                ++curw;
            }
            ctrl_s = code;
        }
        __syncthreads();
        int c = ctrl_s;
        if (c == -1) break;

        if (c == -2) {
            for (int i = tid; i < SEGSZ; i += 1024) {
                int gi = SEGSZ + i;
                if (gi < nlist) {
                    int o = og[gi];
                    soidx[i] = o;
                    const float* bp = bxp + (size_t)o * 4;
                    float b0 = bp[0], b1 = bp[1], b2 = bp[2], b3 = bp[3];
                    sy1[i] = fminf(b0, b2); sy2[i] = fmaxf(b0, b2);
                    sx1[i] = fminf(b1, b3); sx2[i] = fmaxf(b1, b3);
                }
            }
            __syncthreads();
            int kc = keptcnt_s;
            for (int k = 0; k < 2; ++k) {
                int li = tid + k * 1024;
                float y1 = sy1[li], y2 = sy2[li], x1 = sx1[li], x2 = sx2[li];
                float ar = (y2 - y1) * (x2 - x1);
                bool s = false;
                for (int q = 0; q < kc; ++q) {
                    float ih = fmaxf(0.f, fminf(y2, ky2[q]) - fmaxf(y1, ky1[q]));
                    float iw = fmaxf(0.f, fminf(x2, kx2[q]) - fmaxf(x1, kx1[q]));
                    float inter = ih * iw;
                    float uni = (ar + kar[q]) - inter;
                    s = s || (inter > 0.f && inter / uni > IOU_T);
                }
                uint64_t bal = __ballot(s);
                if (lane == 0 && bal) {
                    int word = (SEGSZ + k * 1024 + wv * 64) >> 6;
                    sup[word] |= bal;
                }
            }
            __syncthreads();
            continue;
        }

        int sg = seg_s;
        int cl = c - sg * SEGSZ;
        float cy1 = sy1[cl], cy2 = sy2[cl], cx1 = sx1[cl], cx2 = sx2[cl];
        float car = (cy2 - cy1) * (cx2 - cx1);
        for (int k = 0; k < 2; ++k) {
            int li = tid + k * 1024;
            float y1 = sy1[li], y2 = sy2[li], x1 = sx1[li], x2 = sx2[li];
            float ar = (y2 - y1) * (x2 - x1);
            float ih = fmaxf(0.f, fminf(y2, cy2) - fmaxf(y1, cy1));
            float iw = fmaxf(0.f, fminf(x2, cx2) - fmaxf(x1, cx1));
            float inter = ih * iw;
            float uni = (ar + car) - inter;
            bool s = (inter > 0.f) && (inter / uni > IOU_T);
            uint64_t bal = __ballot(s);
            if (lane == 0 && bal) {
                int word = (sg * SEGSZ + k * 1024 + wv * 64) >> 6;
                sup[word] |= bal;
            }
        }
        __syncthreads();
    }

    if (tid == 0) cnt_out[b] = keptcnt_s;
    for (int i = tid; i < MAXD; i += 1024)
        kidx_out[b * MAXD + i] = (i < keptcnt_s) ? keptidx[i] : 0;
}

extern "C" void kernel_launch(void* const* d_in, const int* in_sizes, int n_in,
                              void* d_out, int out_size, void* d_ws, size_t ws_size,
                              hipStream_t stream) {
    const float* boxes = (const float*)d_in[0];   // [B,N,4]
    const float* cls   = (const float*)d_in[1];   // [B,N,C]
    float* out = (float*)d_out;
    float* out_box = out;                                                  // [B,100,4]
    float* out_cls = out + (size_t)BB * MAXD * 4;                          // [B,100,80]
    float* probs   = out + (size_t)BB * MAXD * 4 + (size_t)BB * MAXD * CC; // [B,N,80]

    char* ws = (char*)d_ws;
    uint64_t* keys = (uint64_t*)(ws + WS_KEYS);

    k_softmax<<<(BB * NN) / 128, 128, 0, stream>>>(cls, probs, keys);

    if (ws_size >= (size_t)WS_NEED) {
        float* y1s = (float*)(ws + WS_Y1S);
        float* x1s = (float*)(ws + WS_X1S);
        float* y2s = (float*)(ws + WS_Y2S);
        float* x2s = (float*)(ws + WS_X2S);
        float* ars = (float*)(ws + WS_ARS);
        int* nlist = (int*)(ws + WS_NLIST);
        int* kidx  = (int*)(ws + WS_KIDX);
        int* cnt   = (int*)(ws + WS_CNT);
        uint64_t* mask = (uint64_t*)(ws + WS_MASK);

        k_part<<<BB, 1024, 0, stream>>>(keys, boxes, y1s, x1s, y2s, x2s, ars, nlist);
        k_iou<<<HW * BB, 1024, 0, stream>>>(y1s, x1s, y2s, x2s, ars, nlist, mask);
        k_sweep<<<BB, 1024, 0, stream>>>(mask, y1s, x1s, y2s, x2s, ars, nlist,
                                         keys, kidx, cnt);
        k_gather<<<(BB * PER_B + 255) / 256, 256, 0, stream>>>(boxes, probs, kidx, cnt,
                                                               out_box, out_cls);
    } else {
        int* kidx = (int*)(ws + (size_t)BB * NN * sizeof(uint64_t));
        int* cnt  = kidx + BB * MAXD;
        k_nms_fb<<<BB, 1024, 0, stream>>>(keys, boxes, kidx, cnt);
        k_gather<<<(BB * PER_B + 255) / 256, 256, 0, stream>>>(boxes, probs, kidx, cnt,
                                                               out_box, out_cls);
    }
}

// Round 8
// 184.074 us; speedup vs baseline: 1.5576x; 1.0877x over previous
//
#include <hip/hip_runtime.h>
#include <cstdint>
#include <cstddef>

#define BB 16
#define NN 4096
#define CC 80
#define MAXD 100
#define IOU_T 0.5f
#define CONF_T 0.5f
#define RSTRIDE 81
#define PER_B (MAXD * 4 + MAXD * CC)   // 8400 output elems per batch
#define NWORDS (NN / 64)
#define BCAP 2048
#define SEGSZ 2048
#define HH 2048                        // head size for mask matrix
#define HW 32                          // head words (HH/64)

// ---- workspace layout (fast path) ----
#define WS_KEYS   0x000000             // [B*N] u64 (og int list overlays)
#define WS_Y1S    0x080000             // [B*N] f32 each
#define WS_X1S    0x0C0000
#define WS_Y2S    0x100000
#define WS_X2S    0x140000
#define WS_ARS    0x180000
#define WS_NLIST  0x1C0000             // [B] int
#define WS_KIDX   0x1C0100             // [B*100] int
#define WS_CNT    0x1C2000             // [B] int
#define WS_MASK   0x200000             // [B*HH*HW] u64 = 8 MB
#define WS_NEED   0xA00000             // 10.5 MB

// ---------------------------------------------------------------------------
// K1: softmax of (10x)^2 per row, one THREAD per row, 128 rows/block.
// numpy pairwise-8 sum DAG for s (bitwise == np); score = IEEE fl(1/s).
// ---------------------------------------------------------------------------
__global__ __launch_bounds__(128) void k_softmax(const float* __restrict__ cls_in,
                                                 float* __restrict__ probs,
                                                 uint64_t* __restrict__ keys) {
#pragma clang fp contract(off)
    __shared__ float buf[128 * RSTRIDE];
    int t = threadIdx.x;
    size_t gbase = (size_t)blockIdx.x * 128 * CC;

    for (int i = t; i < 128 * CC; i += 128) {
        int r = i / CC, c = i - r * CC;
        buf[r * RSTRIDE + c] = cls_in[gbase + i];
    }
    __syncthreads();

    float* row = buf + t * RSTRIDE;

    float m = -3.402823466e+38f;
    for (int c = 0; c < CC; ++c) {
        float y = row[c] * 10.0f;
        float z = y * y;
        m = fmaxf(m, z);
    }
    for (int c = 0; c < CC; ++c) {
        float y = row[c] * 10.0f;
        float z = y * y;
        row[c] = expf(z - m);
    }
    float r8[8];
    #pragma unroll
    for (int j = 0; j < 8; ++j) r8[j] = row[j];
    for (int i = 8; i < CC; i += 8) {
        #pragma unroll
        for (int j = 0; j < 8; ++j) r8[j] += row[i + j];
    }
    float s = ((r8[0] + r8[1]) + (r8[2] + r8[3])) + ((r8[4] + r8[5]) + (r8[6] + r8[7]));

    float score = 1.0f / s;
    for (int c = 0; c < CC; ++c) row[c] = row[c] * score;

    int gw = blockIdx.x * 128 + t;
    unsigned n = (unsigned)(gw & (NN - 1));
    keys[gw] = ((uint64_t)__float_as_uint(score) << 32)
             | (uint64_t)(0xFFFFFFFFu - n);

    __syncthreads();
    for (int i = t; i < 128 * CC; i += 128) {
        int r = i / CC, c = i - r * CC;
        probs[gbase + i] = buf[r * RSTRIDE + c];
    }
}

// ---------------------------------------------------------------------------
// K2: partition + dynamic-size B-sort + fused sorted-corner build.
// One block (1024 thr) per batch; blockIdx.x = b -> XCD b%8 (locality anchor).
// ---------------------------------------------------------------------------
__global__ __launch_bounds__(1024) void k_part(uint64_t* keys,
                                               const float* __restrict__ boxes,
                                               float* __restrict__ y1s, float* __restrict__ x1s,
                                               float* __restrict__ y2s, float* __restrict__ x2s,
                                               float* __restrict__ ars,
                                               int* __restrict__ nlist_g) {
#pragma clang fp contract(off)
    __shared__ uint64_t bbuf[BCAP];
    __shared__ int wsumA[16], wsumB[16];

    const int tid = threadIdx.x, lane = tid & 63, wv = tid >> 6;
    const int b = blockIdx.x;
    const uint64_t* kb = keys + (size_t)b * NN;
    int* og = (int*)(keys + (size_t)b * NN);
    size_t bN = (size_t)b * NN;

    uint64_t myk[4]; bool fa[4], fb[4];
    int asum = 0, bsum = 0;
    for (int k = 0; k < 4; ++k) {
        uint64_t key = kb[4 * tid + k]; myk[k] = key;   // all reads precede barrier
        unsigned hi = (unsigned)(key >> 32);
        fa[k] = (hi == 0x3F800000u);
        fb[k] = (__uint_as_float(hi) > CONF_T) && !fa[k];
        asum += fa[k] ? 1 : 0; bsum += fb[k] ? 1 : 0;
    }
    int ia = asum, ib = bsum;                       // wave-inclusive scans
    for (int off = 1; off < 64; off <<= 1) {
        int va = __shfl_up(ia, off), vb = __shfl_up(ib, off);
        if (lane >= off) { ia += va; ib += vb; }
    }
    if (lane == 63) { wsumA[wv] = ia; wsumB[wv] = ib; }
    __syncthreads();
    int baseA = 0, baseB = 0, cntA = 0, cntB = 0;
    for (int w2 = 0; w2 < 16; ++w2) {
        if (w2 < wv) { baseA += wsumA[w2]; baseB += wsumB[w2]; }
        cntA += wsumA[w2]; cntB += wsumB[w2];
    }
    int pA = baseA + (ia - asum);
    int pB = baseB + (ib - bsum);
    for (int k = 0; k < 4; ++k) {
        if (fa[k]) og[pA++] = 4 * tid + k;          // stable: idx order
        if (fb[k]) { if (pB < BCAP) bbuf[pB] = myk[k]; pB++; }
    }
    int cntBc = cntB < BCAP ? cntB : BCAP;
    int P2 = 64; while (P2 < cntBc) P2 <<= 1;       // dynamic sort size
    for (int i = tid; i < P2; i += 1024) if (i >= cntBc) bbuf[i] = 0;
    __syncthreads();

    for (unsigned k2 = 2; k2 <= (unsigned)P2; k2 <<= 1) {
        for (unsigned j = k2 >> 1; j > 0; j >>= 1) {
            for (unsigned i = tid; i < (unsigned)P2; i += 1024) {
                unsigned p = i ^ j;
                if (p > i) {
                    uint64_t va = bbuf[i], vb = bbuf[p];
                    bool desc = ((i & k2) == 0);
                    if (desc ? (va < vb) : (va > vb)) { bbuf[i] = vb; bbuf[p] = va; }
                }
            }
            __syncthreads();
        }
    }
    for (int i = tid; i < cntBc; i += 1024)
        og[cntA + i] = (int)(0xFFFFFFFFu - (unsigned)(bbuf[i] & 0xFFFFFFFFull));
    int nl = cntA + cntBc;
    if (tid == 0) nlist_g[b] = nl;
    __syncthreads();

    // fused sorted corner/area build (og is L2-hot)
    const float* bxp = boxes + bN * 4;
    for (int i = tid; i < nl; i += 1024) {
        int o = og[i];
        float4 bv = ((const float4*)bxp)[o];
        float y1 = fminf(bv.x, bv.z), y2 = fmaxf(bv.x, bv.z);
        float x1 = fminf(bv.y, bv.w), x2 = fmaxf(bv.y, bv.w);
        y1s[bN + i] = y1; x1s[bN + i] = x1;
        y2s[bN + i] = y2; x2s[bN + i] = x2;
        ars[bN + i] = (y2 - y1) * (x2 - x1);
    }
}

// ---------------------------------------------------------------------------
// K3: head suppression-mask matrix, row-tile blocks + LDS-staged output
// (coalesced 16 KB store; fixes partial-line RMW). x = ti*16+b -> XCD b%8.
// ---------------------------------------------------------------------------
__global__ __launch_bounds__(1024) void k_iou(const float* __restrict__ y1s, const float* __restrict__ x1s,
                                              const float* __restrict__ y2s, const float* __restrict__ x2s,
                                              const float* __restrict__ ars,
                                              const int* __restrict__ nlist_g,
                                              uint64_t* __restrict__ mask) {
#pragma clang fp contract(off)
    __shared__ float cy1[HH], cx1[HH], cy2[HH], cx2[HH], cas[HH];
    __shared__ uint64_t om[64 * HW];
    int x = blockIdx.x;
    int b = x & 15, ti = x >> 4;
    int tid = threadIdx.x, lane = tid & 63, wv = tid >> 6;
    int nl = nlist_g[b];
    int Hc = nl < HH ? nl : HH;
    size_t bN = (size_t)b * NN;

    for (int i = tid; i < HH; i += 1024) {
        bool v = i < Hc;
        cy1[i] = v ? y1s[bN + i] : 0.f;
        cx1[i] = v ? x1s[bN + i] : 0.f;
        cy2[i] = v ? y2s[bN + i] : 0.f;
        cx2[i] = v ? x2s[bN + i] : 0.f;
        cas[i] = v ? ars[bN + i] : 0.f;
    }
    for (int i = tid; i < 64 * HW; i += 1024) om[i] = 0;
    __syncthreads();

    for (int r = wv; r < 64; r += 16) {
        int i = ti * 64 + r;
        if (i >= Hc) continue;
        float a1 = cy1[i], a3 = cx1[i], a2 = cy2[i], a4 = cx2[i], aa = cas[i];
        for (int tj = ti; tj < HW; ++tj) {
            int j = tj * 64 + lane;
            float ih = fmaxf(0.f, fminf(a2, cy2[j]) - fmaxf(a1, cy1[j]));
            float iw = fmaxf(0.f, fminf(a4, cx2[j]) - fmaxf(a3, cx1[j]));
            float inter = ih * iw;
            float uni = (aa + cas[j]) - inter;
            bool s = (j < Hc) && (j > i) && (inter > 0.f) && (inter / uni > IOU_T);
            uint64_t w = __ballot(s);
            if (lane == 0) om[r * HW + tj] = w;
        }
    }
    __syncthreads();

    uint64_t* mdst = mask + ((size_t)b * HH + (size_t)ti * 64) * HW;
    for (int i = tid; i < 64 * HW; i += 1024) mdst[i] = om[i];
}

// ---------------------------------------------------------------------------
// K4 v2: sweep with SPECULATIVE BATCHED phase A.
// Per batch of 16: register-only selection of the 16 lowest live indices,
// then 8 independent paired mask-row loads (2 rows per instr) + parallel
// candidate-data loads, then exact greedy replay in registers (alive-bit
// check handles intra-batch kills). ~7 batched load-latencies total instead
// of ~92 serial ones. Phases B/C unchanged (verified).
// ---------------------------------------------------------------------------
__global__ __launch_bounds__(1024) void k_sweep(const uint64_t* __restrict__ mask,
                                                const float* __restrict__ y1s, const float* __restrict__ x1s,
                                                const float* __restrict__ y2s, const float* __restrict__ x2s,
                                                const float* __restrict__ ars,
                                                const int* __restrict__ nlist_g,
                                                const uint64_t* __restrict__ keys,  // og overlay
                                                int* __restrict__ kidx_out,
                                                int* __restrict__ cnt_out) {
#pragma clang fp contract(off)
    __shared__ float kky1[MAXD], kkx1[MAXD], kky2[MAXD], kkx2[MAXD], kkar[MAXD];
    __shared__ int   kkidx[MAXD];
    __shared__ uint64_t tailw[HW];
    __shared__ int kA_s, ktot_s;

    int b = blockIdx.x;
    int tid = threadIdx.x, lane = tid & 63, wv = tid >> 6;
    int nl = nlist_g[b];
    int Hc = nl < HH ? nl : HH;
    size_t bN = (size_t)b * NN;
    const int* og = (const int*)(keys + bN);
    const uint64_t* mb = mask + (((size_t)b * HH) << 5);

    if (tid == 0) { kA_s = 0; ktot_s = 0; }
    for (int i = tid; i < HW; i += 1024) tailw[i] = 0;
    __syncthreads();

    // ---- phase A: wave0 speculative batched head sweep ----
    if (wv == 0) {
        int lo = 64 * lane;
        uint64_t live;
        if (Hc <= lo) live = 0;
        else if (Hc >= lo + 64) live = ~0ull;
        else live = (1ull << (Hc - lo)) - 1ull;

        int kept = 0;
        bool done = false;
        while (!done && kept < MAXD) {
            // --- select up to 16 lowest live indices (register-only) ---
            uint64_t tmp = live;
            int cand[16];
            int mycand = -1;
            int ncand = 0;
            #pragma unroll
            for (int s2 = 0; s2 < 16; ++s2) {
                uint64_t bal = __ballot(tmp != 0);
                int c = -1;
                if (bal) {
                    int fl = __ffsll((unsigned long long)bal) - 1;
                    uint64_t w0 = __shfl(tmp, fl);
                    int bi = __ffsll((unsigned long long)w0) - 1;
                    c = 64 * fl + bi;
                    if (lane == fl) tmp &= tmp - 1;
                    ncand = s2 + 1;
                }
                cand[s2] = c;
                if (lane == s2) mycand = c;
            }
            if (ncand == 0) break;

            // --- parallel loads: 8 paired mask-row loads + candidate data ---
            uint64_t rw[8];
            #pragma unroll
            for (int p = 0; p < 8; ++p) {
                int ci = (lane < 32) ? cand[2 * p] : cand[2 * p + 1];
                uint64_t r = 0;
                if (ci >= 0) r = mb[(size_t)ci * HW + (lane & 31)];
                rw[p] = r;
            }
            float dy1 = 0.f, dx1 = 0.f, dy2 = 0.f, dx2 = 0.f, dar = 0.f;
            int dog = 0;
            if (lane < 16 && mycand >= 0) {
                dy1 = y1s[bN + mycand]; dx1 = x1s[bN + mycand];
                dy2 = y2s[bN + mycand]; dx2 = x2s[bN + mycand];
                dar = ars[bN + mycand]; dog = og[mycand];
            }

            // --- exact greedy replay over the batch ---
            #pragma unroll
            for (int p = 0; p < 8; ++p) {
                #pragma unroll
                for (int k = 0; k < 2; ++k) {
                    if (!done) {
                        int s = 2 * p + k;
                        int ci = cand[s];
                        if (ci < 0) {
                            done = true;       // batch exhausted; live is empty too
                        } else {
                            int wi = ci >> 6, bi = ci & 63;
                            uint64_t lw = __shfl(live, wi);
                            if ((lw >> bi) & 1ull) {
                                // keep: AND out its suppression row
                                uint64_t rword = __shfl(rw[p], (k << 5) | (lane & 31));
                                live &= ~rword;
                                if (lane == wi) live &= ~(1ull << bi);
                                if (lane == s) {
                                    kky1[kept] = dy1; kkx1[kept] = dx1;
                                    kky2[kept] = dy2; kkx2[kept] = dx2;
                                    kkar[kept] = dar; kkidx[kept] = dog;
                                }
                                ++kept;
                                if (kept >= MAXD) done = true;
                            }
                        }
                    }
                }
            }
            if (ncand < 16) break;   // live fully consumed this batch
        }
        if (lane == 0) { kA_s = kept; ktot_s = kept; }
    }
    __syncthreads();

    // ---- phase B: parallel tail suppression vs head keeps ----
    int kA = kA_s;
    if (nl > HH && kA < MAXD) {
        for (int rep = 0; rep < 2; ++rep) {
            int c = HH + rep * 1024 + tid;
            bool sup = (c >= nl);
            float y1 = y1s[bN + c], x1 = x1s[bN + c];
            float y2 = y2s[bN + c], x2 = x2s[bN + c];
            float ar = ars[bN + c];
            for (int q = 0; q < kA; ++q) {
                float ih = fmaxf(0.f, fminf(y2, kky2[q]) - fmaxf(y1, kky1[q]));
                float iw = fmaxf(0.f, fminf(x2, kkx2[q]) - fmaxf(x1, kkx1[q]));
                float inter = ih * iw;
                float uni = (ar + kkar[q]) - inter;
                sup = sup || (inter > 0.f && inter / uni > IOU_T);
            }
            uint64_t balS = __ballot(!sup);
            if (lane == 0) tailw[rep * 16 + wv] = balS;
        }
    }
    __syncthreads();

    // ---- phase C: wave0 walks surviving tail candidates ----
    if (wv == 0 && nl > HH && kA < MAXD) {
        uint64_t tlive = (lane >= 32) ? tailw[lane - 32] : 0;
        int kept = kA;
        while (kept < MAXD) {
            uint64_t bal = __ballot(tlive != 0);
            if (!bal) break;
            int fl = __ffsll((unsigned long long)bal) - 1;
            uint64_t w0 = __shfl(tlive, fl);
            int bit = __ffsll((unsigned long long)w0) - 1;
            int c = HH + 64 * (fl - 32) + bit;
            if (lane == fl) tlive &= tlive - 1;

            float y1 = y1s[bN + c], x1 = x1s[bN + c];
            float y2 = y2s[bN + c], x2 = x2s[bN + c];
            float ar = ars[bN + c];
            bool hit = false;
            for (int q0 = kA; q0 < kept; q0 += 64) {
                int qi = q0 + lane;
                bool p = false;
                if (qi < kept) {
                    float ih = fmaxf(0.f, fminf(y2, kky2[qi]) - fmaxf(y1, kky1[qi]));
                    float iw = fmaxf(0.f, fminf(x2, kkx2[qi]) - fmaxf(x1, kkx1[qi]));
                    float inter = ih * iw;
                    float uni = (ar + kkar[qi]) - inter;
                    p = (inter > 0.f) && (inter / uni > IOU_T);
                }
                if (__ballot(p)) { hit = true; break; }
            }
            if (!hit) {
                if (lane == 0) {
                    kky1[kept] = y1; kkx1[kept] = x1;
                    kky2[kept] = y2; kkx2[kept] = x2;
                    kkar[kept] = ar; kkidx[kept] = og[c];
                }
                ++kept;
            }
        }
        if (lane == 0) ktot_s = kept;
    }
    __syncthreads();

    int kt = ktot_s;
    if (tid == 0) cnt_out[b] = kt;
    for (int i = tid; i < MAXD; i += 1024)
        kidx_out[b * MAXD + i] = (i < kt) ? kkidx[i] : 0;
}

// ---------------------------------------------------------------------------
// K5: wide parallel gather (unchanged).
// ---------------------------------------------------------------------------
__global__ __launch_bounds__(256) void k_gather(const float* __restrict__ boxes,
                                                const float* __restrict__ probs,
                                                const int* __restrict__ kidx,
                                                const int* __restrict__ cnt,
                                                float* __restrict__ out_box,
                                                float* __restrict__ out_cls) {
    int u = blockIdx.x * 256 + threadIdx.x;
    if (u >= BB * PER_B) return;
    int b = u / PER_B;
    int r = u - b * PER_B;
    int count = cnt[b];
    float val = 0.0f;
    if (r < MAXD * 4) {
        int t = r >> 2, e = r & 3;
        if (t < count) {
            int idx = kidx[b * MAXD + t];
            val = boxes[((size_t)b * NN + idx) * 4 + e];
        }
        out_box[(size_t)b * MAXD * 4 + r] = val;
    } else {
        int q = r - MAXD * 4;
        int t = q / CC, c = q - t * CC;
        if (t < count) {
            int idx = kidx[b * MAXD + t];
            val = probs[((size_t)b * NN + idx) * CC + c];
        }
        out_cls[(size_t)b * MAXD * CC + q] = val;
    }
}

// ---------------------------------------------------------------------------
// FALLBACK (ws too small): round-4 fused k_nms — verified passing.
// ---------------------------------------------------------------------------
__global__ __launch_bounds__(1024) void k_nms_fb(uint64_t* keys,
                                                 const float* __restrict__ boxes,
                                                 int* __restrict__ kidx_out,
                                                 int* __restrict__ cnt_out) {
#pragma clang fp contract(off)
    __shared__ float sy1[SEGSZ], sx1[SEGSZ], sy2[SEGSZ], sx2[SEGSZ];
    __shared__ int   soidx[SEGSZ];
    __shared__ uint64_t bbuf[BCAP];
    __shared__ uint64_t sup[NWORDS];
    __shared__ float ky1[MAXD], kx1[MAXD], ky2[MAXD], kx2[MAXD], kar[MAXD];
    __shared__ int   keptidx[MAXD];
    __shared__ int   wsumA[16], wsumB[16];
    __shared__ int   keptcnt_s, ctrl_s, seg_s;

    const int tid = threadIdx.x, lane = tid & 63, wv = tid >> 6;
    const int b = blockIdx.x;
    const uint64_t* kb = keys + (size_t)b * NN;
    const float* bxp = boxes + (size_t)b * NN * 4;
    int* og = (int*)(keys + (size_t)b * NN);

    uint64_t myk[4]; bool fa[4], fb[4];
    int asum = 0, bsum = 0;
    for (int k = 0; k < 4; ++k) {
        uint64_t key = kb[4 * tid + k]; myk[k] = key;
        unsigned hi = (unsigned)(key >> 32);
        fa[k] = (hi == 0x3F800000u);
        fb[k] = (__uint_as_float(hi) > CONF_T) && !fa[k];
        asum += fa[k] ? 1 : 0; bsum += fb[k] ? 1 : 0;
    }
    int ia = asum, ib = bsum;
    for (int off = 1; off < 64; off <<= 1) {
        int va = __shfl_up(ia, off), vb = __shfl_up(ib, off);
        if (lane >= off) { ia += va; ib += vb; }
    }
    if (lane == 63) { wsumA[wv] = ia; wsumB[wv] = ib; }
    __syncthreads();
    int baseA = 0, baseB = 0, cntA = 0, cntB = 0;
    for (int w2 = 0; w2 < 16; ++w2) {
        if (w2 < wv) { baseA += wsumA[w2]; baseB += wsumB[w2]; }
        cntA += wsumA[w2]; cntB += wsumB[w2];
    }
    int pA = baseA + (ia - asum);
    int pB = baseB + (ib - bsum);
    for (int k = 0; k < 4; ++k) {
        if (fa[k]) og[pA++] = 4 * tid + k;
        if (fb[k]) { if (pB < BCAP) bbuf[pB] = myk[k]; pB++; }
    }
    int cntBc = cntB < BCAP ? cntB : BCAP;
    int nlist = cntA + cntBc;
    if (tid == 0) { keptcnt_s = 0; seg_s = 0; }
    for (int i = tid; i < BCAP; i += 1024) if (i >= cntB) bbuf[i] = 0;
    __syncthreads();

    for (unsigned k2 = 2; k2 <= BCAP; k2 <<= 1) {
        for (unsigned j = k2 >> 1; j > 0; j >>= 1) {
            for (unsigned i = tid; i < BCAP; i += 1024) {
                unsigned p = i ^ j;
                if (p > i) {
                    uint64_t va = bbuf[i], vb = bbuf[p];
                    bool desc = ((i & k2) == 0);
                    if (desc ? (va < vb) : (va > vb)) { bbuf[i] = vb; bbuf[p] = va; }
                }
            }
            __syncthreads();
        }
    }
    for (int i = tid; i < cntBc; i += 1024)
        og[cntA + i] = (int)(0xFFFFFFFFu - (unsigned)(bbuf[i] & 0xFFFFFFFFull));
    if (tid < NWORDS) {
        int lo = tid * 64;
        uint64_t mm;
        if (nlist <= lo) mm = ~0ull;
        else if (nlist >= lo + 64) mm = 0ull;
        else mm = (~0ull) << (nlist - lo);
        sup[tid] = mm;
    }
    __syncthreads();

    for (int i = tid; i < SEGSZ; i += 1024) {
        if (i < nlist) {
            int o = og[i];
            soidx[i] = o;
            const float* bp = bxp + (size_t)o * 4;
            float b0 = bp[0], b1 = bp[1], b2 = bp[2], b3 = bp[3];
            sy1[i] = fminf(b0, b2); sy2[i] = fmaxf(b0, b2);
            sx1[i] = fminf(b1, b3); sx2[i] = fmaxf(b1, b3);
        }
    }
    __syncthreads();

    int curw = 0, segr = 0;
    while (true) {
        if (tid == 0) {
            int code = -1;
            for (;;) {
                int wend = (segr + 1) * (SEGSZ / 64);
                if (curw >= wend) {
                    if (segr == 0 && nlist > SEGSZ) {
                        code = -2; segr = 1; seg_s = 1; curw = SEGSZ / 64;
                    } else code = -1;
                    break;
                }
                uint64_t live = ~sup[curw];
                if (live) {
                    int j = __ffsll((unsigned long long)live) - 1;
                    int sel = curw * 64 + j;
                    int li = sel - segr * SEGSZ;
                    int kc = keptcnt_s;
                    keptidx[kc] = soidx[li];
                    ky1[kc] = sy1[li]; kx1[kc] = sx1[li];
                    ky2[kc] = sy2[li]; kx2[kc] = sx2[li];
                    kar[kc] = (sy2[li] - sy1[li]) * (sx2[li] - sx1[li]);
                    keptcnt_s = kc + 1;
                    sup[curw] |= (1ull << j);
                    code = (kc + 1 >= MAXD) ? -1 : sel;
                    break;
                }
                ++curw;
            }
            ctrl_s = code;
        }
        __syncthreads();
        int c = ctrl_s;
        if (c == -1) break;

        if (c == -2) {
            for (int i = tid; i < SEGSZ; i += 1024) {
                int gi = SEGSZ + i;
                if (gi < nlist) {
                    int o = og[gi];
                    soidx[i] = o;
                    const float* bp = bxp + (size_t)o * 4;
                    float b0 = bp[0], b1 = bp[1], b2 = bp[2], b3 = bp[3];
                    sy1[i] = fminf(b0, b2); sy2[i] = fmaxf(b0, b2);
                    sx1[i] = fminf(b1, b3); sx2[i] = fmaxf(b1, b3);
                }
            }
            __syncthreads();
            int kc = keptcnt_s;
            for (int k = 0; k < 2; ++k) {
                int li = tid + k * 1024;
                float y1 = sy1[li], y2 = sy2[li], x1 = sx1[li], x2 = sx2[li];
                float ar = (y2 - y1) * (x2 - x1);
                bool s = false;
                for (int q = 0; q < kc; ++q) {
                    float ih = fmaxf(0.f, fminf(y2, ky2[q]) - fmaxf(y1, ky1[q]));
                    float iw = fmaxf(0.f, fminf(x2, kx2[q]) - fmaxf(x1, kx1[q]));
                    float inter = ih * iw;
                    float uni = (ar + kar[q]) - inter;
                    s = s || (inter > 0.f && inter / uni > IOU_T);
                }
                uint64_t bal = __ballot(s);
                if (lane == 0 && bal) {
                    int word = (SEGSZ + k * 1024 + wv * 64) >> 6;
                    sup[word] |= bal;
                }
            }
            __syncthreads();
            continue;
        }

        int sg = seg_s;
        int cl = c - sg * SEGSZ;
        float cy1 = sy1[cl], cy2 = sy2[cl], cx1 = sx1[cl], cx2 = sx2[cl];
        float car = (cy2 - cy1) * (cx2 - cx1);
        for (int k = 0; k < 2; ++k) {
            int li = tid + k * 1024;
            float y1 = sy1[li], y2 = sy2[li], x1 = sx1[li], x2 = sx2[li];
            float ar = (y2 - y1) * (x2 - x1);
            float ih = fmaxf(0.f, fminf(y2, cy2) - fmaxf(y1, cy1));
            float iw = fmaxf(0.f, fminf(x2, cx2) - fmaxf(x1, cx1));
            float inter = ih * iw;
            float uni = (ar + car) - inter;
            bool s = (inter > 0.f) && (inter / uni > IOU_T);
            uint64_t bal = __ballot(s);
            if (lane == 0 && bal) {
                int word = (sg * SEGSZ + k * 1024 + wv * 64) >> 6;
                sup[word] |= bal;
            }
        }
        __syncthreads();
    }

    if (tid == 0) cnt_out[b] = keptcnt_s;
    for (int i = tid; i < MAXD; i += 1024)
        kidx_out[b * MAXD + i] = (i < keptcnt_s) ? keptidx[i] : 0;
}

extern "C" void kernel_launch(void* const* d_in, const int* in_sizes, int n_in,
                              void* d_out, int out_size, void* d_ws, size_t ws_size,
                              hipStream_t stream) {
    const float* boxes = (const float*)d_in[0];   // [B,N,4]
    const float* cls   = (const float*)d_in[1];   // [B,N,C]
    float* out = (float*)d_out;
    float* out_box = out;                                                  // [B,100,4]
    float* out_cls = out + (size_t)BB * MAXD * 4;                          // [B,100,80]
    float* probs   = out + (size_t)BB * MAXD * 4 + (size_t)BB * MAXD * CC; // [B,N,80]

    char* ws = (char*)d_ws;
    uint64_t* keys = (uint64_t*)(ws + WS_KEYS);

    k_softmax<<<(BB * NN) / 128, 128, 0, stream>>>(cls, probs, keys);

    if (ws_size >= (size_t)WS_NEED) {
        float* y1s = (float*)(ws + WS_Y1S);
        float* x1s = (float*)(ws + WS_X1S);
        float* y2s = (float*)(ws + WS_Y2S);
        float* x2s = (float*)(ws + WS_X2S);
        float* ars = (float*)(ws + WS_ARS);
        int* nlist = (int*)(ws + WS_NLIST);
        int* kidx  = (int*)(ws + WS_KIDX);
        int* cnt   = (int*)(ws + WS_CNT);
        uint64_t* mask = (uint64_t*)(ws + WS_MASK);

        k_part<<<BB, 1024, 0, stream>>>(keys, boxes, y1s, x1s, y2s, x2s, ars, nlist);
        k_iou<<<HW * BB, 1024, 0, stream>>>(y1s, x1s, y2s, x2s, ars, nlist, mask);
        k_sweep<<<BB, 1024, 0, stream>>>(mask, y1s, x1s, y2s, x2s, ars, nlist,
                                         keys, kidx, cnt);
        k_gather<<<(BB * PER_B + 255) / 256, 256, 0, stream>>>(boxes, probs, kidx, cnt,
                                                               out_box, out_cls);
    } else {
        int* kidx = (int*)(ws + (size_t)BB * NN * sizeof(uint64_t));
        int* cnt  = kidx + BB * MAXD;
        k_nms_fb<<<BB, 1024, 0, stream>>>(keys, boxes, kidx, cnt);
        k_gather<<<(BB * PER_B + 255) / 256, 256, 0, stream>>>(boxes, probs, kidx, cnt,
                                                               out_box, out_cls);
    }
}